// Round 1
// baseline (1925.158 us; speedup 1.0000x reference)
//
#include <hip/hip_runtime.h>
#include <hip/hip_bf16.h>
#include <stdint.h>

#define DEVI __device__ __forceinline__

typedef __attribute__((ext_vector_type(8))) unsigned short us8;
typedef __attribute__((ext_vector_type(8))) __bf16 bf16x8;
typedef __attribute__((ext_vector_type(4))) float f32x4;

#define BB 4
#define CC 192
#define HH 128
#define NPIX 16384
#define MTOT 65536
#define HEADS 6

DEVI float b2f(unsigned short u){ return __uint_as_float(((unsigned)u)<<16); }
DEVI unsigned short f2b(float f){
  unsigned u = __float_as_uint(f);
  return (unsigned short)((u + 0x7fffu + ((u>>16)&1u)) >> 16);
}

DEVI void gload16(const void* g, void* l){
  __builtin_amdgcn_global_load_lds((const __attribute__((address_space(1))) unsigned int*)g,
                                   (__attribute__((address_space(3))) unsigned int*)l,
                                   16, 0, 0);
}

// ---------------- LayerNorm 1: x NCHW f32 -> norm_x (n,c) bf16 ----------------
__global__ __launch_bounds__(256)
void ln1_k(const float* __restrict__ x, const float* __restrict__ lnw,
           const float* __restrict__ lnb, unsigned short* __restrict__ nx)
{
  __shared__ float tile[CC*65];
  __shared__ float stats[64*2];
  int gbase = blockIdx.x * 64;            // global (b*NPIX+n) base
  int b = gbase >> 14; int n0 = gbase & (NPIX-1);
  for (int idx = threadIdx.x; idx < CC*64; idx += 256){
    int c = idx >> 6, j = idx & 63;
    tile[c*65 + j] = x[((size_t)b*CC + c)*NPIX + n0 + j];
  }
  __syncthreads();
  if (threadIdx.x < 64){
    int j = threadIdx.x;
    float s = 0.f, ss = 0.f;
    for (int c = 0; c < CC; c++){ float v = tile[c*65 + j]; s += v; ss += v*v; }
    float mu = s * (1.f/CC);
    float var = ss * (1.f/CC) - mu*mu;
    stats[j*2] = mu; stats[j*2+1] = rsqrtf(var + 1e-6f);
  }
  __syncthreads();
  for (int idx = threadIdx.x; idx < CC*64; idx += 256){
    int c = idx % CC, j = idx / CC;
    float v = (tile[c*65 + j] - stats[j*2]) * stats[j*2+1] * lnw[c] + lnb[c];
    nx[(size_t)(gbase + j)*CC + c] = f2b(v);
  }
}

// ---------------- LayerNorm 2: x2 (n,c) f32 -> nx (n,c) bf16 ----------------
__global__ __launch_bounds__(256)
void ln2_k(const float* __restrict__ x2, const float* __restrict__ lnw,
           const float* __restrict__ lnb, unsigned short* __restrict__ nx)
{
  int gm = blockIdx.x*4 + (threadIdx.x >> 6);
  int lane = threadIdx.x & 63;
  const float* row = x2 + (size_t)gm*CC;
  float v0 = row[lane], v1 = row[lane+64], v2 = row[lane+128];
  float s = v0+v1+v2, ss = v0*v0+v1*v1+v2*v2;
  #pragma unroll
  for (int o = 32; o >= 1; o >>= 1){
    s  += __shfl_xor(s,  o);
    ss += __shfl_xor(ss, o);
  }
  float mu = s * (1.f/CC);
  float rstd = rsqrtf(ss*(1.f/CC) - mu*mu + 1e-6f);
  unsigned short* o0 = nx + (size_t)gm*CC;
  o0[lane]     = f2b((v0-mu)*rstd*lnw[lane]     + lnb[lane]);
  o0[lane+64]  = f2b((v1-mu)*rstd*lnw[lane+64]  + lnb[lane+64]);
  o0[lane+128] = f2b((v2-mu)*rstd*lnw[lane+128] + lnb[lane+128]);
}

// ---------------- MFMA GEMM: Out[m][co] = sum_k A[m][k]*W[co][k] ----------------
// A: (n,c)-layout bf16, rows strideA; W: [co][Ktot] bf16.
// NSLICES=9: implicit 3x3 conv (k = s*sliceC + ci, shift s with zero pad).
// EPI 0: out bf16 (+optional bias[co]); EPI 1: x2 = xNCHW + a*acc (f32, (n,c));
// EPI 2: d_out NCHW = x2(n,c) + (1-a)*acc.
template<int EPI, int NSLICES>
__global__ __launch_bounds__(256, 2)
void gemm_k(const unsigned short* __restrict__ A, int strideA,
            const unsigned short* __restrict__ W, int Ktot, int sliceC,
            int NcolsW, int NcolsStore, int outStride, int colBlocks,
            unsigned short* __restrict__ outB,
            const float* __restrict__ bias,
            const float* __restrict__ res,
            float* __restrict__ outF,
            const float* __restrict__ alphaP,
            const unsigned short* __restrict__ zerop)
{
  __shared__ unsigned short lds[2*128*64];
  unsigned short* ldsA = lds;
  unsigned short* ldsB = lds + 128*64;

  const int tid = threadIdx.x;
  const int lane = tid & 63;
  const int wv = tid >> 6;
  const int bid = blockIdx.x;
  const int mblk = bid / colBlocks;
  const int nblk = bid - mblk*colBlocks;
  const int m0 = mblk*128, co0 = nblk*128;

  const int jT = lane & 7;
  int rowT[4];
  #pragma unroll
  for (int i = 0; i < 4; i++) rowT[i] = ((wv*4 + i)*64 + lane) >> 3;

  const unsigned short* bsrc[4];
  #pragma unroll
  for (int i = 0; i < 4; i++){
    int co = co0 + rowT[i];
    int jj = jT ^ (rowT[i] & 7);
    bsrc[i] = (co < NcolsW) ? (W + (size_t)co*Ktot + (jj << 3))
                            : (zerop + (lane << 3));
  }

  const unsigned short* asrc[4];
  int gmA[4], jjA[4];
  #pragma unroll
  for (int i = 0; i < 4; i++){
    gmA[i] = m0 + rowT[i];
    jjA[i] = jT ^ (rowT[i] & 7);
    asrc[i] = A + (size_t)gmA[i]*strideA + (jjA[i] << 3);
  }

  f32x4 acc[4][4] = {};
  int ci0 = 0, s = 0, dy = -1, dx = -1;

  for (int k0 = 0; k0 < Ktot; k0 += 64){
    if constexpr (NSLICES == 1){
      #pragma unroll
      for (int i = 0; i < 4; i++){
        gload16(asrc[i], (char*)ldsA + (wv*4 + i)*1024);
        asrc[i] += 64;
      }
    } else {
      #pragma unroll
      for (int i = 0; i < 4; i++){
        int gm = gmA[i];
        int np = gm & (NPIX-1);
        int hh = np >> 7, ww = np & 127;
        int h2 = hh + dy, w2 = ww + dx;
        const unsigned short* src = ((unsigned)h2 < 128u && (unsigned)w2 < 128u)
          ? (A + (size_t)(gm + dy*HH + dx)*strideA + ci0 + (jjA[i] << 3))
          : (zerop + (lane << 3));
        gload16(src, (char*)ldsA + (wv*4 + i)*1024);
      }
    }
    #pragma unroll
    for (int i = 0; i < 4; i++){
      gload16(bsrc[i], (char*)ldsB + (wv*4 + i)*1024);
      bsrc[i] += 64;
    }
    asm volatile("s_waitcnt vmcnt(0)" ::: "memory");
    __syncthreads();

    #pragma unroll
    for (int kk = 0; kk < 2; kk++){
      bf16x8 af[4], bfr[4];
      int kb = kk*64 + ((lane >> 4) << 4);
      #pragma unroll
      for (int mi = 0; mi < 4; mi++){
        int rm = (wv >> 1)*64 + mi*16 + (lane & 15);
        int off = rm*128 + (kb ^ ((rm & 7) << 4));
        af[mi] = *(const bf16x8*)((const char*)ldsA + off);
      }
      #pragma unroll
      for (int ni = 0; ni < 4; ni++){
        int rb = (wv & 1)*64 + ni*16 + (lane & 15);
        int off = rb*128 + (kb ^ ((rb & 7) << 4));
        bfr[ni] = *(const bf16x8*)((const char*)ldsB + off);
      }
      #pragma unroll
      for (int mi = 0; mi < 4; mi++)
        #pragma unroll
        for (int ni = 0; ni < 4; ni++)
          acc[mi][ni] = __builtin_amdgcn_mfma_f32_16x16x32_bf16(af[mi], bfr[ni], acc[mi][ni], 0, 0, 0);
    }
    __syncthreads();

    ci0 += 64;
    if (NSLICES > 1 && ci0 == sliceC){ ci0 = 0; s++; dy = s/3 - 1; dx = s - (s/3)*3 - 1; }
  }

  float alpha = 0.f;
  if (EPI == 1) alpha = *alphaP;
  if (EPI == 2) alpha = 1.f - *alphaP;
  const int colb = co0 + (wv & 1)*64;
  const int rowb = m0 + (wv >> 1)*64;
  #pragma unroll
  for (int mi = 0; mi < 4; mi++){
    int r0 = rowb + mi*16 + ((lane >> 4) << 2);
    #pragma unroll
    for (int ni = 0; ni < 4; ni++){
      int co = colb + ni*16 + (lane & 15);
      if (co < NcolsStore){
        float bv = (EPI == 0 && bias) ? bias[co] : 0.f;
        #pragma unroll
        for (int r = 0; r < 4; r++){
          int gm = r0 + r;
          float v = acc[mi][ni][r];
          if constexpr (EPI == 0){
            outB[(size_t)gm*outStride + co] = f2b(v + bv);
          } else if constexpr (EPI == 1){
            int b = gm >> 14, np = gm & (NPIX-1);
            outF[(size_t)gm*CC + co] = res[((size_t)b*CC + co)*NPIX + np] + alpha*v;
          } else {
            int b = gm >> 14, np = gm & (NPIX-1);
            outF[((size_t)b*CC + co)*NPIX + np] = res[(size_t)gm*CC + co] + alpha*v;
          }
        }
      }
    }
  }
}

// ---------------- Depthwise 3x3 (+optional SiLU), (n,c) bf16 ----------------
__global__ __launch_bounds__(256)
void dw_k(const unsigned short* __restrict__ src, int strideS, int coloff,
          const float* __restrict__ wt, int wtoff, int nchv, int nchReal, int doSilu,
          unsigned short* __restrict__ dst, int strideD)
{
  int idx = blockIdx.x*256 + threadIdx.x;
  int gm = idx / nchv;
  int cb = idx - gm*nchv;
  int c = cb*8;
  int np = gm & (NPIX-1);
  int hh = np >> 7, ww = np & 127;
  float acc[8] = {0,0,0,0,0,0,0,0};
  #pragma unroll
  for (int s = 0; s < 9; s++){
    int dy = s/3 - 1, dx = s%3 - 1;
    int h2 = hh + dy, w2 = ww + dx;
    if ((unsigned)h2 < 128u && (unsigned)w2 < 128u){
      us8 t = *(const us8*)(src + (size_t)(gm + dy*HH + dx)*strideS + coloff + c);
      #pragma unroll
      for (int j = 0; j < 8; j++){
        float wv = (c + j < nchReal) ? wt[(size_t)(wtoff + c + j)*9 + s] : 0.f;
        acc[j] += b2f(t[j]) * wv;
      }
    }
  }
  us8 o;
  #pragma unroll
  for (int j = 0; j < 8; j++){
    float v = acc[j];
    if (doSilu) v = v / (1.f + __expf(-v));
    o[j] = f2b(v);
  }
  *(us8*)(dst + (size_t)gm*strideD + c) = o;
}

// ---------------- per-(b,c) sum of squares over n (partials) ----------------
__global__ __launch_bounds__(192)
void sumsq_k(const unsigned short* __restrict__ q, float* __restrict__ part)
{
  int b = blockIdx.x >> 5, ch = blockIdx.x & 31;
  int c = threadIdx.x;
  const unsigned short* base = q + ((size_t)b*NPIX + ch*512)*CC + c;
  float acc = 0.f;
  for (int r = 0; r < 512; r++){ float v = b2f(base[(size_t)r*CC]); acc += v*v; }
  part[(size_t)(b*32 + ch)*CC + c] = acc;
}

// ---------------- QK^T partials: S[c][d] = sum_n q[c,n]k[d,n] ----------------
__global__ __launch_bounds__(256)
void pairdot_k(const unsigned short* __restrict__ qb, const unsigned short* __restrict__ kb,
               int stride, float* __restrict__ Spart)
{
  __shared__ float qs[32][129];
  __shared__ float ks[32][129];
  int bh = blockIdx.x >> 3;
  int chunk = blockIdx.x & 7;
  int b = bh / HEADS, h = bh - b*HEADS;
  int t = threadIdx.x;
  int cP = t >> 3;
  int dg = t & 7;
  size_t gm0 = (size_t)b*NPIX + chunk*2048;
  int r = t >> 1, hf = t & 1;
  float acc0=0, acc1=0, acc2=0, acc3=0;
  for (int sub = 0; sub < 16; sub++){
    __syncthreads();
    {
      const unsigned short* pq = qb + (gm0 + sub*128 + r)*stride + h*32 + hf*16;
      const unsigned short* pk = kb + (gm0 + sub*128 + r)*stride + h*32 + hf*16;
      us8 a0 = *(const us8*)pq; us8 a1 = *(const us8*)(pq + 8);
      us8 b0 = *(const us8*)pk; us8 b1 = *(const us8*)(pk + 8);
      #pragma unroll
      for (int j = 0; j < 8; j++){
        qs[hf*16 + j][r]     = b2f(a0[j]);
        qs[hf*16 + 8 + j][r] = b2f(a1[j]);
        ks[hf*16 + j][r]     = b2f(b0[j]);
        ks[hf*16 + 8 + j][r] = b2f(b1[j]);
      }
    }
    __syncthreads();
    for (int n = 0; n < 128; n++){
      float qv = qs[cP][n];
      acc0 += qv * ks[dg*4+0][n];
      acc1 += qv * ks[dg*4+1][n];
      acc2 += qv * ks[dg*4+2][n];
      acc3 += qv * ks[dg*4+3][n];
    }
  }
  float* o = Spart + (size_t)blockIdx.x*1024 + cP*32 + dg*4;
  o[0]=acc0; o[1]=acc1; o[2]=acc2; o[3]=acc3;
}

// ---------------- softmax(cfa)+softmax(pos) combine ----------------
__global__ __launch_bounds__(64)
void smax_k(const float* __restrict__ Spos, const float* __restrict__ Scfa,
            const float* __restrict__ qnp, const float* __restrict__ knp,
            const float* __restrict__ temp, float* __restrict__ att)
{
  int bh = blockIdx.x; int b = bh / HEADS, h = bh - b*HEADS;
  __shared__ float kn[32];
  int t = threadIdx.x;
  if (t < 32){
    float ss = 0.f;
    for (int ck = 0; ck < 32; ck++) ss += knp[((size_t)b*32 + ck)*CC + h*32 + t];
    kn[t] = fmaxf(sqrtf(ss), 1e-12f);
  }
  __syncthreads();
  if (t >= 32) return;
  int c = t;
  float ssq = 0.f;
  for (int ck = 0; ck < 32; ck++) ssq += qnp[((size_t)b*32 + ck)*CC + h*32 + c];
  float qn = fmaxf(sqrtf(ssq), 1e-12f);
  float rowS[32], rowP[32];
  #pragma unroll
  for (int d = 0; d < 32; d++){
    float sv = 0.f, pv = 0.f;
    for (int ck = 0; ck < 8; ck++){
      sv += Scfa[(size_t)(bh*8 + ck)*1024 + c*32 + d];
      pv += Spos[(size_t)(bh*8 + ck)*1024 + c*32 + d];
    }
    rowS[d] = sv; rowP[d] = pv;
  }
  float tv = temp[h];
  float m1 = -3e38f, m2 = -3e38f;
  #pragma unroll
  for (int d = 0; d < 32; d++){
    rowS[d] = rowS[d] / (qn*kn[d]) * tv;
    m1 = fmaxf(m1, rowS[d]);
    m2 = fmaxf(m2, rowP[d]);
  }
  float s1 = 0.f, s2 = 0.f;
  #pragma unroll
  for (int d = 0; d < 32; d++){
    rowS[d] = __expf(rowS[d] - m1); s1 += rowS[d];
    rowP[d] = __expf(rowP[d] - m2); s2 += rowP[d];
  }
  float r1 = 1.f/s1, r2 = 1.f/s2;
  #pragma unroll
  for (int d = 0; d < 32; d++)
    att[(size_t)bh*1024 + c*32 + d] = rowS[d]*r1 + rowP[d]*r2;
}

// ---------------- PV: outT[n][c] = sum_d att[c][d] * v[d][n] ----------------
__global__ __launch_bounds__(256)
void pv_k(const float* __restrict__ att, const unsigned short* __restrict__ vd,
          unsigned short* __restrict__ outT)
{
  __shared__ float As[32][33];
  int bh = blockIdx.x >> 8; int mc = blockIdx.x & 255;
  int b = bh / HEADS, h = bh - b*HEADS;
  int t = threadIdx.x;
  for (int i = t; i < 1024; i += 256) As[i >> 5][i & 31] = att[(size_t)bh*1024 + i];
  __syncthreads();
  int gm = b*NPIX + mc*64 + (t >> 2);
  int cq = t & 3;
  const unsigned short* vp = vd + (size_t)gm*CC + h*32;
  float acc[8] = {0,0,0,0,0,0,0,0};
  for (int d = 0; d < 32; d++){
    float vv = b2f(vp[d]);
    #pragma unroll
    for (int j = 0; j < 8; j++) acc[j] += As[cq*8 + j][d] * vv;
  }
  us8 o;
  #pragma unroll
  for (int j = 0; j < 8; j++) o[j] = f2b(acc[j]);
  *(us8*)(outT + (size_t)gm*CC + h*32 + cq*8) = o;
}

// ---------------- weight prep ----------------
__global__ void castcopy_k(const float* __restrict__ s, unsigned short* __restrict__ d, int n){
  int i = blockIdx.x*256 + threadIdx.x; if (i < n) d[i] = f2b(s[i]);
}
__global__ void prepselin_k(const float* __restrict__ s, unsigned short* __restrict__ d){
  int i = blockIdx.x*256 + threadIdx.x;
  if (i >= 510*1728) return;
  int co = i / 1728, rem = i - co*1728;
  int sl = rem / 192, ci = rem - sl*192;
  d[i] = f2b(s[(size_t)(co*192 + ci)*9 + sl]);
}
__global__ void prepselout_k(const float* __restrict__ s, unsigned short* __restrict__ d){
  int i = blockIdx.x*256 + threadIdx.x;
  if (i >= 192*4608) return;
  int co = i / 4608, rem = i - co*4608;
  int sl = rem / 512, ci = rem - sl*512;
  d[i] = (ci < 510) ? f2b(s[(size_t)(co*510 + ci)*9 + sl]) : (unsigned short)0;
}
__global__ void prepbias_k(const float* __restrict__ pq, const float* __restrict__ pk,
                           const float* __restrict__ pe, float* __restrict__ bias){
  int r = blockIdx.x*64 + threadIdx.x;
  if (r >= 384) return;
  const float* Wp = (r < 192) ? pq : pk;
  int co = (r < 192) ? r : r - 192;
  float s = 0.f;
  for (int ci = 0; ci < 192; ci++) s += Wp[co*192 + ci]*pe[ci];
  bias[r] = s;
}

// ---------------- launch ----------------
extern "C" void kernel_launch(void* const* d_in, const int* in_sizes, int n_in,
                              void* d_out, int out_size, void* d_ws, size_t ws_size,
                              hipStream_t stream)
{
  const float* x       = (const float*)d_in[0];
  const float* ln_w    = (const float*)d_in[1];
  const float* ln_b    = (const float*)d_in[2];
  const float* temp    = (const float*)d_in[3];
  const float* q_w     = (const float*)d_in[4];
  const float* q_dw    = (const float*)d_in[5];
  const float* kv_w    = (const float*)d_in[6];
  const float* kv_dw   = (const float*)d_in[7];
  const float* proj_w  = (const float*)d_in[8];
  const float* pos_e   = (const float*)d_in[9];
  const float* posq_w  = (const float*)d_in[10];
  const float* posk_w  = (const float*)d_in[11];
  const float* selin_w = (const float*)d_in[12];
  const float* seldw_w = (const float*)d_in[13];
  const float* selout_w= (const float*)d_in[14];
  const float* alphaP  = (const float*)d_in[15];

  char* ws = (char*)d_ws;
  // small region
  unsigned short* zerop  = (unsigned short*)(ws + 0);         // 4KB zeros
  float* biasF           = (float*)(ws + 4096);
  float* Spos            = (float*)(ws + 8192);               // 24*8*1024 f32
  float* Scfa            = (float*)(ws + 794624);
  float* qnp             = (float*)(ws + 1581056);            // 4*32*192 f32
  float* knp             = (float*)(ws + 1679360);
  float* att             = (float*)(ws + 1777664);            // 24*1024 f32
  unsigned short* Wa     = (unsigned short*)(ws + 2097152);   // 576x192
  unsigned short* Wb     = (unsigned short*)(ws + 2318336);   // 384x192
  unsigned short* Wproj  = (unsigned short*)(ws + 2465792);   // 192x192
  unsigned short* Wselin = (unsigned short*)(ws + 2539520);   // 510x1728
  unsigned short* Wselout= (unsigned short*)(ws + 4302080);   // 192x4608
  // big regions (lifetimes disjoint within region). Total need ~216MB.
  unsigned short* normx  = (unsigned short*)(ws + 8388608);   // S1: normx / qd / nx
  unsigned short* qd     = normx;
  unsigned short* nx     = normx;
  unsigned short* pqpk   = (unsigned short*)(ws + 33554432);  // S2: pqpk / qkv / outT / g
  unsigned short* qkv    = pqpk;
  unsigned short* outT   = pqpk;
  unsigned short* g      = pqpk;
  unsigned short* kd     = (unsigned short*)(ws + 109051904); // S3: kd,vd / x2
  unsigned short* vd     = (unsigned short*)(ws + 134217728);
  float*          x2     = (float*)(ws + 109051904);
  unsigned short* g2     = (unsigned short*)(ws + 159383552); // S4

  hipMemsetAsync(zerop, 0, 4096, stream);

  // weight prep
  castcopy_k<<<144, 256, 0, stream>>>(q_w,   Wa,        36864);
  castcopy_k<<<288, 256, 0, stream>>>(kv_w,  Wa+36864,  73728);
  castcopy_k<<<144, 256, 0, stream>>>(posq_w,Wb,        36864);
  castcopy_k<<<144, 256, 0, stream>>>(posk_w,Wb+36864,  36864);
  castcopy_k<<<144, 256, 0, stream>>>(proj_w,Wproj,     36864);
  prepselin_k<<<3443, 256, 0, stream>>>(selin_w, Wselin);
  prepselout_k<<<3456, 256, 0, stream>>>(selout_w, Wselout);
  prepbias_k<<<6, 64, 0, stream>>>(posq_w, posk_w, pos_e, biasF);

  // LN1
  ln1_k<<<1024, 256, 0, stream>>>(x, ln_w, ln_b, normx);
  // pos_q/pos_k GEMM (+pos_embed bias)
  gemm_k<0,1><<<512*3, 256, 0, stream>>>(normx, 192, Wb, 192, 192, 384, 384, 384, 3,
                                         pqpk, biasF, nullptr, nullptr, nullptr, zerop);
  // pos logits
  pairdot_k<<<192, 256, 0, stream>>>(pqpk, pqpk + 192, 384, Spos);
  // q/k/v GEMM
  gemm_k<0,1><<<512*5, 256, 0, stream>>>(normx, 192, Wa, 192, 192, 576, 576, 576, 5,
                                         qkv, nullptr, nullptr, nullptr, nullptr, zerop);
  // depthwise q,k,v
  dw_k<<<6144, 256, 0, stream>>>(qkv, 576, 0,   q_dw,  0,   24, 192, 0, qd, 192);
  dw_k<<<6144, 256, 0, stream>>>(qkv, 576, 192, kv_dw, 0,   24, 192, 0, kd, 192);
  dw_k<<<6144, 256, 0, stream>>>(qkv, 576, 384, kv_dw, 192, 24, 192, 0, vd, 192);
  // l2 norms (partials)
  sumsq_k<<<128, 192, 0, stream>>>(qd, qnp);
  sumsq_k<<<128, 192, 0, stream>>>(kd, knp);
  // cfa logits
  pairdot_k<<<192, 256, 0, stream>>>(qd, kd, 192, Scfa);
  // softmaxes + combine
  smax_k<<<24, 64, 0, stream>>>(Spos, Scfa, qnp, knp, temp, att);
  // PV
  pv_k<<<24*256, 256, 0, stream>>>(att, vd, outT);
  // proj + residual -> x2 (f32, (n,c))
  gemm_k<1,1><<<512*2, 256, 0, stream>>>(outT, 192, Wproj, 192, 192, 192, 192, 0, 2,
                                         nullptr, nullptr, x, x2, alphaP, zerop);
  // LN2
  ln2_k<<<16384, 256, 0, stream>>>(x2, ln_w, ln_b, nx);
  // SEL in conv3x3 (implicit GEMM, K=1728)
  gemm_k<0,9><<<512*4, 256, 0, stream>>>(nx, 192, Wselin, 1728, 192, 510, 512, 512, 4,
                                         g, nullptr, nullptr, nullptr, nullptr, zerop);
  // SEL depthwise + SiLU
  dw_k<<<16384, 256, 0, stream>>>(g, 512, 0, seldw_w, 0, 64, 510, 1, g2, 512);
  // SEL out conv3x3 (K=4608) + final residual -> d_out NCHW
  gemm_k<2,9><<<512*2, 256, 0, stream>>>(g2, 512, Wselout, 4608, 512, 192, 192, 0, 2,
                                         nullptr, nullptr, x2, (float*)d_out, alphaP, zerop);
}

// Round 2
// 1008.643 us; speedup vs baseline: 1.9087x; 1.9087x over previous
//
#include <hip/hip_runtime.h>
#include <hip/hip_bf16.h>
#include <stdint.h>

#define DEVI __device__ __forceinline__

typedef __attribute__((ext_vector_type(8))) unsigned short us8;
typedef __attribute__((ext_vector_type(8))) __bf16 bf16x8;
typedef __attribute__((ext_vector_type(4))) float f32x4;

#define BB 4
#define CC 192
#define HH 128
#define NPIX 16384
#define MTOT 65536
#define HEADS 6

DEVI float b2f(unsigned short u){ return __uint_as_float(((unsigned)u)<<16); }
DEVI unsigned short f2b(float f){
  unsigned u = __float_as_uint(f);
  return (unsigned short)((u + 0x7fffu + ((u>>16)&1u)) >> 16);
}

DEVI void gload16(const void* g, void* l){
  __builtin_amdgcn_global_load_lds((const __attribute__((address_space(1))) unsigned int*)g,
                                   (__attribute__((address_space(3))) unsigned int*)l,
                                   16, 0, 0);
}

// ---------------- LayerNorm 1: x NCHW f32 -> norm_x (n,c) bf16 ----------------
__global__ __launch_bounds__(256)
void ln1_k(const float* __restrict__ x, const float* __restrict__ lnw,
           const float* __restrict__ lnb, unsigned short* __restrict__ nx)
{
  __shared__ float tile[CC*65];
  __shared__ float stats[64*2];
  int gbase = blockIdx.x * 64;            // global (b*NPIX+n) base
  int b = gbase >> 14; int n0 = gbase & (NPIX-1);
  for (int idx = threadIdx.x; idx < CC*64; idx += 256){
    int c = idx >> 6, j = idx & 63;
    tile[c*65 + j] = x[((size_t)b*CC + c)*NPIX + n0 + j];
  }
  __syncthreads();
  if (threadIdx.x < 64){
    int j = threadIdx.x;
    float s = 0.f, ss = 0.f;
    for (int c = 0; c < CC; c++){ float v = tile[c*65 + j]; s += v; ss += v*v; }
    float mu = s * (1.f/CC);
    float var = ss * (1.f/CC) - mu*mu;
    stats[j*2] = mu; stats[j*2+1] = rsqrtf(var + 1e-6f);
  }
  __syncthreads();
  for (int idx = threadIdx.x; idx < CC*64; idx += 256){
    int c = idx % CC, j = idx / CC;
    float v = (tile[c*65 + j] - stats[j*2]) * stats[j*2+1] * lnw[c] + lnb[c];
    nx[(size_t)(gbase + j)*CC + c] = f2b(v);
  }
}

// ---------------- LayerNorm 2: x2 (n,c) f32 -> nx (n,c) bf16 ----------------
__global__ __launch_bounds__(256)
void ln2_k(const float* __restrict__ x2, const float* __restrict__ lnw,
           const float* __restrict__ lnb, unsigned short* __restrict__ nx)
{
  int gm = blockIdx.x*4 + (threadIdx.x >> 6);
  int lane = threadIdx.x & 63;
  const float* row = x2 + (size_t)gm*CC;
  float v0 = row[lane], v1 = row[lane+64], v2 = row[lane+128];
  float s = v0+v1+v2, ss = v0*v0+v1*v1+v2*v2;
  #pragma unroll
  for (int o = 32; o >= 1; o >>= 1){
    s  += __shfl_xor(s,  o);
    ss += __shfl_xor(ss, o);
  }
  float mu = s * (1.f/CC);
  float rstd = rsqrtf(ss*(1.f/CC) - mu*mu + 1e-6f);
  unsigned short* o0 = nx + (size_t)gm*CC;
  o0[lane]     = f2b((v0-mu)*rstd*lnw[lane]     + lnb[lane]);
  o0[lane+64]  = f2b((v1-mu)*rstd*lnw[lane+64]  + lnb[lane+64]);
  o0[lane+128] = f2b((v2-mu)*rstd*lnw[lane+128] + lnb[lane+128]);
}

// ---------------- MFMA GEMM: Out[m][co] = sum_k A[m][k]*W[co][k] ----------------
template<int EPI, int NSLICES>
__global__ __launch_bounds__(256, 2)
void gemm_k(const unsigned short* __restrict__ A, int strideA,
            const unsigned short* __restrict__ W, int Ktot, int sliceC,
            int NcolsW, int NcolsStore, int outStride, int colBlocks,
            unsigned short* __restrict__ outB,
            const float* __restrict__ bias,
            const float* __restrict__ res,
            float* __restrict__ outF,
            const float* __restrict__ alphaP,
            const unsigned short* __restrict__ zerop)
{
  __shared__ unsigned short lds[2*128*64];
  unsigned short* ldsA = lds;
  unsigned short* ldsB = lds + 128*64;

  const int tid = threadIdx.x;
  const int lane = tid & 63;
  const int wv = tid >> 6;
  const int bid = blockIdx.x;
  const int mblk = bid / colBlocks;
  const int nblk = bid - mblk*colBlocks;
  const int m0 = mblk*128, co0 = nblk*128;

  const int jT = lane & 7;
  int rowT[4];
  #pragma unroll
  for (int i = 0; i < 4; i++) rowT[i] = ((wv*4 + i)*64 + lane) >> 3;

  const unsigned short* bsrc[4];
  #pragma unroll
  for (int i = 0; i < 4; i++){
    int co = co0 + rowT[i];
    int jj = jT ^ (rowT[i] & 7);
    bsrc[i] = (co < NcolsW) ? (W + (size_t)co*Ktot + (jj << 3))
                            : (zerop + (lane << 3));
  }

  const unsigned short* asrc[4];
  int gmA[4], jjA[4];
  #pragma unroll
  for (int i = 0; i < 4; i++){
    gmA[i] = m0 + rowT[i];
    jjA[i] = jT ^ (rowT[i] & 7);
    asrc[i] = A + (size_t)gmA[i]*strideA + (jjA[i] << 3);
  }

  f32x4 acc[4][4] = {};
  int ci0 = 0, s = 0, dy = -1, dx = -1;

  for (int k0 = 0; k0 < Ktot; k0 += 64){
    if constexpr (NSLICES == 1){
      #pragma unroll
      for (int i = 0; i < 4; i++){
        gload16(asrc[i], (char*)ldsA + (wv*4 + i)*1024);
        asrc[i] += 64;
      }
    } else {
      #pragma unroll
      for (int i = 0; i < 4; i++){
        int gm = gmA[i];
        int np = gm & (NPIX-1);
        int hh = np >> 7, ww = np & 127;
        int h2 = hh + dy, w2 = ww + dx;
        const unsigned short* src = ((unsigned)h2 < 128u && (unsigned)w2 < 128u)
          ? (A + (size_t)(gm + dy*HH + dx)*strideA + ci0 + (jjA[i] << 3))
          : (zerop + (lane << 3));
        gload16(src, (char*)ldsA + (wv*4 + i)*1024);
      }
    }
    #pragma unroll
    for (int i = 0; i < 4; i++){
      gload16(bsrc[i], (char*)ldsB + (wv*4 + i)*1024);
      bsrc[i] += 64;
    }
    asm volatile("s_waitcnt vmcnt(0)" ::: "memory");
    __syncthreads();

    #pragma unroll
    for (int kk = 0; kk < 2; kk++){
      bf16x8 af[4], bfr[4];
      int kb = kk*64 + ((lane >> 4) << 4);
      #pragma unroll
      for (int mi = 0; mi < 4; mi++){
        int rm = (wv >> 1)*64 + mi*16 + (lane & 15);
        int off = rm*128 + (kb ^ ((rm & 7) << 4));
        af[mi] = *(const bf16x8*)((const char*)ldsA + off);
      }
      #pragma unroll
      for (int ni = 0; ni < 4; ni++){
        int rb = (wv & 1)*64 + ni*16 + (lane & 15);
        int off = rb*128 + (kb ^ ((rb & 7) << 4));
        bfr[ni] = *(const bf16x8*)((const char*)ldsB + off);
      }
      #pragma unroll
      for (int mi = 0; mi < 4; mi++)
        #pragma unroll
        for (int ni = 0; ni < 4; ni++)
          acc[mi][ni] = __builtin_amdgcn_mfma_f32_16x16x32_bf16(af[mi], bfr[ni], acc[mi][ni], 0, 0, 0);
    }
    __syncthreads();

    ci0 += 64;
    if (NSLICES > 1 && ci0 == sliceC){ ci0 = 0; s++; dy = s/3 - 1; dx = s - (s/3)*3 - 1; }
  }

  float alpha = 0.f;
  if (EPI == 1) alpha = *alphaP;
  if (EPI == 2) alpha = 1.f - *alphaP;
  const int colb = co0 + (wv & 1)*64;
  const int rowb = m0 + (wv >> 1)*64;
  #pragma unroll
  for (int mi = 0; mi < 4; mi++){
    int r0 = rowb + mi*16 + ((lane >> 4) << 2);
    #pragma unroll
    for (int ni = 0; ni < 4; ni++){
      int co = colb + ni*16 + (lane & 15);
      if (co < NcolsStore){
        float bv = (EPI == 0 && bias) ? bias[co] : 0.f;
        #pragma unroll
        for (int r = 0; r < 4; r++){
          int gm = r0 + r;
          float v = acc[mi][ni][r];
          if constexpr (EPI == 0){
            outB[(size_t)gm*outStride + co] = f2b(v + bv);
          } else if constexpr (EPI == 1){
            int b = gm >> 14, np = gm & (NPIX-1);
            outF[(size_t)gm*CC + co] = res[((size_t)b*CC + co)*NPIX + np] + alpha*v;
          } else {
            int b = gm >> 14, np = gm & (NPIX-1);
            outF[((size_t)b*CC + co)*NPIX + np] = res[(size_t)gm*CC + co] + alpha*v;
          }
        }
      }
    }
  }
}

// ---------------- Depthwise 3x3 (+optional SiLU), (n,c) bf16, [s][c] weights ----------------
template<int NCHV, int DOSILU>
__global__ __launch_bounds__(256)
void dw_k(const unsigned short* __restrict__ src, int strideS,
          const float* __restrict__ wtT, int wstride,
          unsigned short* __restrict__ dst, int strideD)
{
  int idx = blockIdx.x*256 + threadIdx.x;
  int gm = idx / NCHV;
  int cb = idx - gm*NCHV;
  int c = cb*8;
  int np = gm & (NPIX-1);
  int hh = np >> 7, ww = np & 127;
  float acc[8] = {0,0,0,0,0,0,0,0};
  #pragma unroll
  for (int s = 0; s < 9; s++){
    int dy = s/3 - 1, dx = s%3 - 1;
    int h2 = hh + dy, w2 = ww + dx;
    if ((unsigned)h2 < 128u && (unsigned)w2 < 128u){
      us8 t = *(const us8*)(src + (size_t)(gm + dy*HH + dx)*strideS + c);
      f32x4 w0 = *(const f32x4*)(wtT + s*wstride + c);
      f32x4 w1 = *(const f32x4*)(wtT + s*wstride + c + 4);
      #pragma unroll
      for (int j = 0; j < 4; j++){
        acc[j]   += b2f(t[j])   * w0[j];
        acc[4+j] += b2f(t[4+j]) * w1[j];
      }
    }
  }
  us8 o;
  #pragma unroll
  for (int j = 0; j < 8; j++){
    float v = acc[j];
    if (DOSILU) v = v / (1.f + __expf(-v));
    o[j] = f2b(v);
  }
  *(us8*)(dst + (size_t)gm*strideD + c) = o;
}

// ---------------- per-(b,c) sum of squares over n (partials) ----------------
__global__ __launch_bounds__(192)
void sumsq_k(const unsigned short* __restrict__ q, int stride, float* __restrict__ part)
{
  int b = blockIdx.x >> 5, ch = blockIdx.x & 31;
  int c = threadIdx.x;
  const unsigned short* base = q + ((size_t)b*NPIX + ch*512)*stride + c;
  float acc = 0.f;
  for (int r = 0; r < 512; r++){ float v = b2f(base[(size_t)r*stride]); acc += v*v; }
  part[(size_t)(b*32 + ch)*CC + c] = acc;
}

// ---------------- QK^T partials: S[c][d] = sum_n q[c,n]k[d,n] ----------------
__global__ __launch_bounds__(256)
void pairdot_k(const unsigned short* __restrict__ qb, const unsigned short* __restrict__ kb,
               int stride, float* __restrict__ Spart)
{
  __shared__ float qs[32][129];
  __shared__ float ks[32][129];
  int bh = blockIdx.x >> 3;
  int chunk = blockIdx.x & 7;
  int b = bh / HEADS, h = bh - b*HEADS;
  int t = threadIdx.x;
  int cP = t >> 3;
  int dg = t & 7;
  size_t gm0 = (size_t)b*NPIX + chunk*2048;
  int r = t >> 1, hf = t & 1;
  float acc0=0, acc1=0, acc2=0, acc3=0;
  for (int sub = 0; sub < 16; sub++){
    __syncthreads();
    {
      const unsigned short* pq = qb + (gm0 + sub*128 + r)*stride + h*32 + hf*16;
      const unsigned short* pk = kb + (gm0 + sub*128 + r)*stride + h*32 + hf*16;
      us8 a0 = *(const us8*)pq; us8 a1 = *(const us8*)(pq + 8);
      us8 b0 = *(const us8*)pk; us8 b1 = *(const us8*)(pk + 8);
      #pragma unroll
      for (int j = 0; j < 8; j++){
        qs[hf*16 + j][r]     = b2f(a0[j]);
        qs[hf*16 + 8 + j][r] = b2f(a1[j]);
        ks[hf*16 + j][r]     = b2f(b0[j]);
        ks[hf*16 + 8 + j][r] = b2f(b1[j]);
      }
    }
    __syncthreads();
    for (int n = 0; n < 128; n++){
      float qv = qs[cP][n];
      acc0 += qv * ks[dg*4+0][n];
      acc1 += qv * ks[dg*4+1][n];
      acc2 += qv * ks[dg*4+2][n];
      acc3 += qv * ks[dg*4+3][n];
    }
  }
  float* o = Spart + (size_t)blockIdx.x*1024 + cP*32 + dg*4;
  o[0]=acc0; o[1]=acc1; o[2]=acc2; o[3]=acc3;
}

// ---------------- softmax(cfa)+softmax(pos) combine ----------------
__global__ __launch_bounds__(64)
void smax_k(const float* __restrict__ Spos, const float* __restrict__ Scfa,
            const float* __restrict__ qnp, const float* __restrict__ knp,
            const float* __restrict__ temp, float* __restrict__ att)
{
  int bh = blockIdx.x; int b = bh / HEADS, h = bh - b*HEADS;
  __shared__ float kn[32];
  int t = threadIdx.x;
  if (t < 32){
    float ss = 0.f;
    for (int ck = 0; ck < 32; ck++) ss += knp[((size_t)b*32 + ck)*CC + h*32 + t];
    kn[t] = fmaxf(sqrtf(ss), 1e-12f);
  }
  __syncthreads();
  if (t >= 32) return;
  int c = t;
  float ssq = 0.f;
  for (int ck = 0; ck < 32; ck++) ssq += qnp[((size_t)b*32 + ck)*CC + h*32 + c];
  float qn = fmaxf(sqrtf(ssq), 1e-12f);
  float rowS[32], rowP[32];
  #pragma unroll
  for (int d = 0; d < 32; d++){
    float sv = 0.f, pv = 0.f;
    for (int ck = 0; ck < 8; ck++){
      sv += Scfa[(size_t)(bh*8 + ck)*1024 + c*32 + d];
      pv += Spos[(size_t)(bh*8 + ck)*1024 + c*32 + d];
    }
    rowS[d] = sv; rowP[d] = pv;
  }
  float tv = temp[h];
  float m1 = -3e38f, m2 = -3e38f;
  #pragma unroll
  for (int d = 0; d < 32; d++){
    rowS[d] = rowS[d] / (qn*kn[d]) * tv;
    m1 = fmaxf(m1, rowS[d]);
    m2 = fmaxf(m2, rowP[d]);
  }
  float s1 = 0.f, s2 = 0.f;
  #pragma unroll
  for (int d = 0; d < 32; d++){
    rowS[d] = __expf(rowS[d] - m1); s1 += rowS[d];
    rowP[d] = __expf(rowP[d] - m2); s2 += rowP[d];
  }
  float r1 = 1.f/s1, r2 = 1.f/s2;
  #pragma unroll
  for (int d = 0; d < 32; d++)
    att[(size_t)bh*1024 + c*32 + d] = rowS[d]*r1 + rowP[d]*r2;
}

// ---------------- PV: outT[n][c] = sum_d att[c][d] * v[d][n] ----------------
__global__ __launch_bounds__(256)
void pv_k(const float* __restrict__ att, const unsigned short* __restrict__ vd, int stride,
          unsigned short* __restrict__ outT)
{
  __shared__ float As[32][33];
  int bh = blockIdx.x >> 8; int mc = blockIdx.x & 255;
  int b = bh / HEADS, h = bh - b*HEADS;
  int t = threadIdx.x;
  for (int i = t; i < 1024; i += 256) As[i >> 5][i & 31] = att[(size_t)bh*1024 + i];
  __syncthreads();
  int gm = b*NPIX + mc*64 + (t >> 2);
  int cq = t & 3;
  const unsigned short* vp = vd + (size_t)gm*stride + h*32;
  float acc[8] = {0,0,0,0,0,0,0,0};
  for (int d = 0; d < 32; d++){
    float vv = b2f(vp[d]);
    #pragma unroll
    for (int j = 0; j < 8; j++) acc[j] += As[cq*8 + j][d] * vv;
  }
  us8 o;
  #pragma unroll
  for (int j = 0; j < 8; j++) o[j] = f2b(acc[j]);
  *(us8*)(outT + (size_t)gm*CC + h*32 + cq*8) = o;
}

// ---------------- weight prep ----------------
__global__ void castcopy_k(const float* __restrict__ s, unsigned short* __restrict__ d, int n){
  int i = blockIdx.x*256 + threadIdx.x; if (i < n) d[i] = f2b(s[i]);
}
__global__ void prepselin_k(const float* __restrict__ s, unsigned short* __restrict__ d){
  int i = blockIdx.x*256 + threadIdx.x;
  if (i >= 510*1728) return;
  int co = i / 1728, rem = i - co*1728;
  int sl = rem / 192, ci = rem - sl*192;
  d[i] = f2b(s[(size_t)(co*192 + ci)*9 + sl]);
}
__global__ void prepselout_k(const float* __restrict__ s, unsigned short* __restrict__ d){
  int i = blockIdx.x*256 + threadIdx.x;
  if (i >= 192*4608) return;
  int co = i / 4608, rem = i - co*4608;
  int sl = rem / 512, ci = rem - sl*512;
  d[i] = (ci < 510) ? f2b(s[(size_t)(co*510 + ci)*9 + sl]) : (unsigned short)0;
}
__global__ void prepbias_k(const float* __restrict__ pq, const float* __restrict__ pk,
                           const float* __restrict__ pe, float* __restrict__ bias){
  int r = blockIdx.x*64 + threadIdx.x;
  if (r >= 384) return;
  const float* Wp = (r < 192) ? pq : pk;
  int co = (r < 192) ? r : r - 192;
  float s = 0.f;
  for (int ci = 0; ci < 192; ci++) s += Wp[co*192 + ci]*pe[ci];
  bias[r] = s;
}
// dw weights -> [s][c] transposed layouts (qkv fused 576; sel padded 512)
__global__ void prepdwT_k(const float* __restrict__ qdw, const float* __restrict__ kvdw,
                          const float* __restrict__ seldw,
                          float* __restrict__ wqkv, float* __restrict__ wsel){
  int i = blockIdx.x*256 + threadIdx.x;
  if (i < 9*576){
    int s = i / 576, c = i - s*576;
    wqkv[i] = (c < 192) ? qdw[c*9 + s] : kvdw[(size_t)(c-192)*9 + s];
  }
  int j = i - 9*576;
  if (j >= 0 && j < 9*512){
    int s = j / 512, c = j - s*512;
    wsel[j] = (c < 510) ? seldw[(size_t)c*9 + s] : 0.f;
  }
}

// ---------------- launch ----------------
extern "C" void kernel_launch(void* const* d_in, const int* in_sizes, int n_in,
                              void* d_out, int out_size, void* d_ws, size_t ws_size,
                              hipStream_t stream)
{
  const float* x       = (const float*)d_in[0];
  const float* ln_w    = (const float*)d_in[1];
  const float* ln_b    = (const float*)d_in[2];
  const float* temp    = (const float*)d_in[3];
  const float* q_w     = (const float*)d_in[4];
  const float* q_dw    = (const float*)d_in[5];
  const float* kv_w    = (const float*)d_in[6];
  const float* kv_dw   = (const float*)d_in[7];
  const float* proj_w  = (const float*)d_in[8];
  const float* pos_e   = (const float*)d_in[9];
  const float* posq_w  = (const float*)d_in[10];
  const float* posk_w  = (const float*)d_in[11];
  const float* selin_w = (const float*)d_in[12];
  const float* seldw_w = (const float*)d_in[13];
  const float* selout_w= (const float*)d_in[14];
  const float* alphaP  = (const float*)d_in[15];

  char* ws = (char*)d_ws;
  unsigned short* zerop  = (unsigned short*)(ws + 0);         // 4KB zeros
  float* biasF           = (float*)(ws + 4096);
  float* Spos            = (float*)(ws + 8192);               // 24*8*1024 f32
  float* Scfa            = (float*)(ws + 794624);
  float* qnp             = (float*)(ws + 1581056);            // 4*32*192 f32
  float* knp             = (float*)(ws + 1679360);
  float* att             = (float*)(ws + 1777664);            // 24*1024 f32
  unsigned short* Wa     = (unsigned short*)(ws + 2097152);   // 576x192
  unsigned short* Wb     = (unsigned short*)(ws + 2318336);   // 384x192
  unsigned short* Wproj  = (unsigned short*)(ws + 2465792);   // 192x192
  unsigned short* Wselin = (unsigned short*)(ws + 2539520);   // 510x1728
  unsigned short* Wselout= (unsigned short*)(ws + 4302080);   // 192x4608
  float* WdwQKV          = (float*)(ws + 6071552);            // 9x576 f32
  float* WdwSEL          = (float*)(ws + 6092288);            // 9x512 f32
  // big regions
  unsigned short* normx  = (unsigned short*)(ws + 8388608);   // S1: normx / nx
  unsigned short* nx     = normx;
  unsigned short* pqpk   = (unsigned short*)(ws + 33554432);  // S2: pqpk / qkv / outT / g
  unsigned short* qkv    = pqpk;
  unsigned short* outT   = pqpk;
  unsigned short* g      = pqpk;
  unsigned short* qkvd   = (unsigned short*)(ws + 109051904); // S3: qkvd(75.5MB) / x2(50MB)
  float*          x2     = (float*)(ws + 109051904);
  unsigned short* g2     = (unsigned short*)(ws + 192937984); // S4 (67MB)

  hipMemsetAsync(zerop, 0, 4096, stream);

  // weight prep
  castcopy_k<<<144, 256, 0, stream>>>(q_w,   Wa,        36864);
  castcopy_k<<<288, 256, 0, stream>>>(kv_w,  Wa+36864,  73728);
  castcopy_k<<<144, 256, 0, stream>>>(posq_w,Wb,        36864);
  castcopy_k<<<144, 256, 0, stream>>>(posk_w,Wb+36864,  36864);
  castcopy_k<<<144, 256, 0, stream>>>(proj_w,Wproj,     36864);
  prepselin_k<<<3443, 256, 0, stream>>>(selin_w, Wselin);
  prepselout_k<<<3456, 256, 0, stream>>>(selout_w, Wselout);
  prepbias_k<<<6, 64, 0, stream>>>(posq_w, posk_w, pos_e, biasF);
  prepdwT_k<<<39, 256, 0, stream>>>(q_dw, kv_dw, seldw_w, WdwQKV, WdwSEL);

  // LN1
  ln1_k<<<1024, 256, 0, stream>>>(x, ln_w, ln_b, normx);
  // pos_q/pos_k GEMM (+pos_embed bias)
  gemm_k<0,1><<<512*3, 256, 0, stream>>>(normx, 192, Wb, 192, 192, 384, 384, 384, 3,
                                         pqpk, biasF, nullptr, nullptr, nullptr, zerop);
  // pos logits
  pairdot_k<<<192, 256, 0, stream>>>(pqpk, pqpk + 192, 384, Spos);
  // q/k/v GEMM
  gemm_k<0,1><<<512*5, 256, 0, stream>>>(normx, 192, Wa, 192, 192, 576, 576, 576, 5,
                                         qkv, nullptr, nullptr, nullptr, nullptr, zerop);
  // fused depthwise q,k,v -> qkvd (n,576)
  dw_k<72,0><<<18432, 256, 0, stream>>>(qkv, 576, WdwQKV, 576, qkvd, 576);
  // l2 norms (partials)
  sumsq_k<<<128, 192, 0, stream>>>(qkvd,       576, qnp);
  sumsq_k<<<128, 192, 0, stream>>>(qkvd + 192, 576, knp);
  // cfa logits
  pairdot_k<<<192, 256, 0, stream>>>(qkvd, qkvd + 192, 576, Scfa);
  // softmaxes + combine
  smax_k<<<24, 64, 0, stream>>>(Spos, Scfa, qnp, knp, temp, att);
  // PV
  pv_k<<<24*256, 256, 0, stream>>>(att, qkvd + 384, 576, outT);
  // proj + residual -> x2 (f32, (n,c))
  gemm_k<1,1><<<512*2, 256, 0, stream>>>(outT, 192, Wproj, 192, 192, 192, 192, 0, 2,
                                         nullptr, nullptr, x, x2, alphaP, zerop);
  // LN2
  ln2_k<<<16384, 256, 0, stream>>>(x2, ln_w, ln_b, nx);
  // SEL in conv3x3 (implicit GEMM, K=1728)
  gemm_k<0,9><<<512*4, 256, 0, stream>>>(nx, 192, Wselin, 1728, 192, 510, 512, 512, 4,
                                         g, nullptr, nullptr, nullptr, nullptr, zerop);
  // SEL depthwise + SiLU
  dw_k<64,1><<<16384, 256, 0, stream>>>(g, 512, WdwSEL, 512, g2, 512);
  // SEL out conv3x3 (K=4608) + final residual -> d_out NCHW
  gemm_k<2,9><<<512*2, 256, 0, stream>>>(g2, 512, Wselout, 4608, 512, 192, 192, 0, 2,
                                         nullptr, nullptr, x2, (float*)d_out, alphaP, zerop);
}

// Round 3
// 939.610 us; speedup vs baseline: 2.0489x; 1.0735x over previous
//
#include <hip/hip_runtime.h>
#include <hip/hip_bf16.h>
#include <stdint.h>

#define DEVI __device__ __forceinline__

typedef __attribute__((ext_vector_type(8))) unsigned short us8;
typedef __attribute__((ext_vector_type(8))) __bf16 bf16x8;
typedef __attribute__((ext_vector_type(4))) float f32x4;

#define BB 4
#define CC 192
#define HH 128
#define NPIX 16384
#define MTOT 65536
#define HEADS 6

DEVI float b2f(unsigned short u){ return __uint_as_float(((unsigned)u)<<16); }
DEVI unsigned short f2b(float f){
  unsigned u = __float_as_uint(f);
  return (unsigned short)((u + 0x7fffu + ((u>>16)&1u)) >> 16);
}

DEVI void gload16(const void* g, void* l){
  __builtin_amdgcn_global_load_lds((const __attribute__((address_space(1))) unsigned int*)g,
                                   (__attribute__((address_space(3))) unsigned int*)l,
                                   16, 0, 0);
}

// ---------------- LayerNorm 1: x NCHW f32 -> norm_x (n,c) bf16 ----------------
__global__ __launch_bounds__(256)
void ln1_k(const float* __restrict__ x, const float* __restrict__ lnw,
           const float* __restrict__ lnb, unsigned short* __restrict__ nx)
{
  __shared__ float tile[CC*65];
  __shared__ float stats[64*2];
  int gbase = blockIdx.x * 64;            // global (b*NPIX+n) base
  int b = gbase >> 14; int n0 = gbase & (NPIX-1);
  for (int idx = threadIdx.x; idx < CC*64; idx += 256){
    int c = idx >> 6, j = idx & 63;
    tile[c*65 + j] = x[((size_t)b*CC + c)*NPIX + n0 + j];
  }
  __syncthreads();
  if (threadIdx.x < 64){
    int j = threadIdx.x;
    float s = 0.f, ss = 0.f;
    for (int c = 0; c < CC; c++){ float v = tile[c*65 + j]; s += v; ss += v*v; }
    float mu = s * (1.f/CC);
    float var = ss * (1.f/CC) - mu*mu;
    stats[j*2] = mu; stats[j*2+1] = rsqrtf(var + 1e-6f);
  }
  __syncthreads();
  for (int idx = threadIdx.x; idx < CC*64; idx += 256){
    int c = idx % CC, j = idx / CC;
    float v = (tile[c*65 + j] - stats[j*2]) * stats[j*2+1] * lnw[c] + lnb[c];
    nx[(size_t)(gbase + j)*CC + c] = f2b(v);
  }
}

// ---------------- LayerNorm 2: x2 (n,c) f32 -> nx (n,c) bf16 ----------------
__global__ __launch_bounds__(256)
void ln2_k(const float* __restrict__ x2, const float* __restrict__ lnw,
           const float* __restrict__ lnb, unsigned short* __restrict__ nx)
{
  int gm = blockIdx.x*4 + (threadIdx.x >> 6);
  int lane = threadIdx.x & 63;
  const float* row = x2 + (size_t)gm*CC;
  float v0 = row[lane], v1 = row[lane+64], v2 = row[lane+128];
  float s = v0+v1+v2, ss = v0*v0+v1*v1+v2*v2;
  #pragma unroll
  for (int o = 32; o >= 1; o >>= 1){
    s  += __shfl_xor(s,  o);
    ss += __shfl_xor(ss, o);
  }
  float mu = s * (1.f/CC);
  float rstd = rsqrtf(ss*(1.f/CC) - mu*mu + 1e-6f);
  unsigned short* o0 = nx + (size_t)gm*CC;
  o0[lane]     = f2b((v0-mu)*rstd*lnw[lane]     + lnb[lane]);
  o0[lane+64]  = f2b((v1-mu)*rstd*lnw[lane+64]  + lnb[lane+64]);
  o0[lane+128] = f2b((v2-mu)*rstd*lnw[lane+128] + lnb[lane+128]);
}

// ---------------- MFMA GEMM: Out[m][co] = sum_k A[m][k]*W[co][k] ----------------
// NSLICES=9: implicit 3x3 conv; K-chunk order = (ci-block OUTER, slice INNER)
// so the 9 shifted reads of the same rows are temporally adjacent (L2 hits).
// W layout for NSLICES=9 must be [co][cib][s][ci64] to match.
template<int EPI, int NSLICES>
__global__ __launch_bounds__(256, 2)
void gemm_k(const unsigned short* __restrict__ A, int strideA,
            const unsigned short* __restrict__ W, int Ktot, int sliceC,
            int NcolsW, int NcolsStore, int outStride, int colBlocks,
            unsigned short* __restrict__ outB,
            const float* __restrict__ bias,
            const float* __restrict__ res,
            float* __restrict__ outF,
            const float* __restrict__ alphaP,
            const unsigned short* __restrict__ zerop)
{
  __shared__ unsigned short lds[2*128*64];
  unsigned short* ldsA = lds;
  unsigned short* ldsB = lds + 128*64;

  const int tid = threadIdx.x;
  const int lane = tid & 63;
  const int wv = tid >> 6;
  // XCD-chunked bijective swizzle (grid % 8 == 0 for all launches)
  const int q8 = gridDim.x >> 3;
  const int bid = (blockIdx.x & 7)*q8 + (blockIdx.x >> 3);
  const int mblk = bid / colBlocks;
  const int nblk = bid - mblk*colBlocks;
  const int m0 = mblk*128, co0 = nblk*128;

  const int jT = lane & 7;
  int rowT[4];
  #pragma unroll
  for (int i = 0; i < 4; i++) rowT[i] = ((wv*4 + i)*64 + lane) >> 3;

  const unsigned short* bsrc[4];
  #pragma unroll
  for (int i = 0; i < 4; i++){
    int co = co0 + rowT[i];
    int jj = jT ^ (rowT[i] & 7);
    bsrc[i] = (co < NcolsW) ? (W + (size_t)co*Ktot + (jj << 3))
                            : (zerop + (lane << 3));
  }

  const unsigned short* asrc[4];
  int gmA[4], jjA[4];
  #pragma unroll
  for (int i = 0; i < 4; i++){
    gmA[i] = m0 + rowT[i];
    jjA[i] = jT ^ (rowT[i] & 7);
    asrc[i] = A + (size_t)gmA[i]*strideA + (jjA[i] << 3);
  }

  f32x4 acc[4][4] = {};
  int ci0 = 0, s = 0, dy = -1, dx = -1;

  for (int k0 = 0; k0 < Ktot; k0 += 64){
    if constexpr (NSLICES == 1){
      #pragma unroll
      for (int i = 0; i < 4; i++){
        gload16(asrc[i], (char*)ldsA + (wv*4 + i)*1024);
        asrc[i] += 64;
      }
    } else {
      #pragma unroll
      for (int i = 0; i < 4; i++){
        int gm = gmA[i];
        int np = gm & (NPIX-1);
        int hh = np >> 7, ww = np & 127;
        int h2 = hh + dy, w2 = ww + dx;
        const unsigned short* src = ((unsigned)h2 < 128u && (unsigned)w2 < 128u)
          ? (A + (size_t)(gm + dy*HH + dx)*strideA + ci0 + (jjA[i] << 3))
          : (zerop + (lane << 3));
        gload16(src, (char*)ldsA + (wv*4 + i)*1024);
      }
    }
    #pragma unroll
    for (int i = 0; i < 4; i++){
      gload16(bsrc[i], (char*)ldsB + (wv*4 + i)*1024);
      bsrc[i] += 64;
    }
    asm volatile("s_waitcnt vmcnt(0)" ::: "memory");
    __syncthreads();

    #pragma unroll
    for (int kk = 0; kk < 2; kk++){
      bf16x8 af[4], bfr[4];
      int kb = kk*64 + ((lane >> 4) << 4);
      #pragma unroll
      for (int mi = 0; mi < 4; mi++){
        int rm = (wv >> 1)*64 + mi*16 + (lane & 15);
        int off = rm*128 + (kb ^ ((rm & 7) << 4));
        af[mi] = *(const bf16x8*)((const char*)ldsA + off);
      }
      #pragma unroll
      for (int ni = 0; ni < 4; ni++){
        int rb = (wv & 1)*64 + ni*16 + (lane & 15);
        int off = rb*128 + (kb ^ ((rb & 7) << 4));
        bfr[ni] = *(const bf16x8*)((const char*)ldsB + off);
      }
      #pragma unroll
      for (int mi = 0; mi < 4; mi++)
        #pragma unroll
        for (int ni = 0; ni < 4; ni++)
          acc[mi][ni] = __builtin_amdgcn_mfma_f32_16x16x32_bf16(af[mi], bfr[ni], acc[mi][ni], 0, 0, 0);
    }
    __syncthreads();

    if constexpr (NSLICES > 1){
      s++; if (s == 9){ s = 0; ci0 += 64; }
      dy = s/3 - 1; dx = s - (s/3)*3 - 1;
    }
  }
  (void)sliceC;

  float alpha = 0.f;
  if (EPI == 1) alpha = *alphaP;
  if (EPI == 2) alpha = 1.f - *alphaP;
  const int colb = co0 + (wv & 1)*64;
  const int rowb = m0 + (wv >> 1)*64;
  #pragma unroll
  for (int mi = 0; mi < 4; mi++){
    int r0 = rowb + mi*16 + ((lane >> 4) << 2);
    #pragma unroll
    for (int ni = 0; ni < 4; ni++){
      int co = colb + ni*16 + (lane & 15);
      if (co < NcolsStore){
        float bv = (EPI == 0 && bias) ? bias[co] : 0.f;
        #pragma unroll
        for (int r = 0; r < 4; r++){
          int gm = r0 + r;
          float v = acc[mi][ni][r];
          if constexpr (EPI == 0){
            outB[(size_t)gm*outStride + co] = f2b(v + bv);
          } else if constexpr (EPI == 1){
            int b = gm >> 14, np = gm & (NPIX-1);
            outF[(size_t)gm*CC + co] = res[((size_t)b*CC + co)*NPIX + np] + alpha*v;
          } else {
            int b = gm >> 14, np = gm & (NPIX-1);
            outF[((size_t)b*CC + co)*NPIX + np] = res[(size_t)gm*CC + co] + alpha*v;
          }
        }
      }
    }
  }
}

// ---------------- Depthwise 3x3 (+optional SiLU), (n,c) bf16, [s][c] weights ----------------
template<int NCHV, int DOSILU>
__global__ __launch_bounds__(256)
void dw_k(const unsigned short* __restrict__ src, int strideS,
          const float* __restrict__ wtT, int wstride,
          unsigned short* __restrict__ dst, int strideD)
{
  const int q8 = gridDim.x >> 3;
  const int bid = (blockIdx.x & 7)*q8 + (blockIdx.x >> 3);
  int idx = bid*256 + threadIdx.x;
  int gm = idx / NCHV;
  int cb = idx - gm*NCHV;
  int c = cb*8;
  int np = gm & (NPIX-1);
  int hh = np >> 7, ww = np & 127;
  float acc[8] = {0,0,0,0,0,0,0,0};
  #pragma unroll
  for (int s = 0; s < 9; s++){
    int dy = s/3 - 1, dx = s%3 - 1;
    int h2 = hh + dy, w2 = ww + dx;
    if ((unsigned)h2 < 128u && (unsigned)w2 < 128u){
      us8 t = *(const us8*)(src + (size_t)(gm + dy*HH + dx)*strideS + c);
      f32x4 w0 = *(const f32x4*)(wtT + s*wstride + c);
      f32x4 w1 = *(const f32x4*)(wtT + s*wstride + c + 4);
      #pragma unroll
      for (int j = 0; j < 4; j++){
        acc[j]   += b2f(t[j])   * w0[j];
        acc[4+j] += b2f(t[4+j]) * w1[j];
      }
    }
  }
  us8 o;
  #pragma unroll
  for (int j = 0; j < 8; j++){
    float v = acc[j];
    if (DOSILU) v = v / (1.f + __expf(-v));
    o[j] = f2b(v);
  }
  *(us8*)(dst + (size_t)gm*strideD + c) = o;
}

// ---------------- per-(b,c) sum of squares over n (partials) ----------------
__global__ __launch_bounds__(192)
void sumsq_k(const unsigned short* __restrict__ q, int stride, float* __restrict__ part)
{
  int b = blockIdx.x >> 5, ch = blockIdx.x & 31;
  int c = threadIdx.x;
  const unsigned short* base = q + ((size_t)b*NPIX + ch*512)*stride + c;
  float acc = 0.f;
  for (int r = 0; r < 512; r++){ float v = b2f(base[(size_t)r*stride]); acc += v*v; }
  part[(size_t)(b*32 + ch)*CC + c] = acc;
}

// ---------------- QK^T partials: S[c][d] = sum_n q[c,n]k[d,n] ----------------
__global__ __launch_bounds__(256)
void pairdot_k(const unsigned short* __restrict__ qb, const unsigned short* __restrict__ kb,
               int stride, float* __restrict__ Spart)
{
  __shared__ float qs[32][129];
  __shared__ float ks[32][129];
  int bh = blockIdx.x >> 3;
  int chunk = blockIdx.x & 7;
  int b = bh / HEADS, h = bh - b*HEADS;
  int t = threadIdx.x;
  int cP = t >> 3;
  int dg = t & 7;
  size_t gm0 = (size_t)b*NPIX + chunk*2048;
  int r = t >> 1, hf = t & 1;
  float acc0=0, acc1=0, acc2=0, acc3=0;
  for (int sub = 0; sub < 16; sub++){
    __syncthreads();
    {
      const unsigned short* pq = qb + (gm0 + sub*128 + r)*stride + h*32 + hf*16;
      const unsigned short* pk = kb + (gm0 + sub*128 + r)*stride + h*32 + hf*16;
      us8 a0 = *(const us8*)pq; us8 a1 = *(const us8*)(pq + 8);
      us8 b0 = *(const us8*)pk; us8 b1 = *(const us8*)(pk + 8);
      #pragma unroll
      for (int j = 0; j < 8; j++){
        qs[hf*16 + j][r]     = b2f(a0[j]);
        qs[hf*16 + 8 + j][r] = b2f(a1[j]);
        ks[hf*16 + j][r]     = b2f(b0[j]);
        ks[hf*16 + 8 + j][r] = b2f(b1[j]);
      }
    }
    __syncthreads();
    for (int n = 0; n < 128; n++){
      float qv = qs[cP][n];
      acc0 += qv * ks[dg*4+0][n];
      acc1 += qv * ks[dg*4+1][n];
      acc2 += qv * ks[dg*4+2][n];
      acc3 += qv * ks[dg*4+3][n];
    }
  }
  float* o = Spart + (size_t)blockIdx.x*1024 + cP*32 + dg*4;
  o[0]=acc0; o[1]=acc1; o[2]=acc2; o[3]=acc3;
}

// ---------------- softmax(cfa)+softmax(pos) combine ----------------
__global__ __launch_bounds__(64)
void smax_k(const float* __restrict__ Spos, const float* __restrict__ Scfa,
            const float* __restrict__ qnp, const float* __restrict__ knp,
            const float* __restrict__ temp, float* __restrict__ att)
{
  int bh = blockIdx.x; int b = bh / HEADS, h = bh - b*HEADS;
  __shared__ float kn[32];
  int t = threadIdx.x;
  if (t < 32){
    float ss = 0.f;
    for (int ck = 0; ck < 32; ck++) ss += knp[((size_t)b*32 + ck)*CC + h*32 + t];
    kn[t] = fmaxf(sqrtf(ss), 1e-12f);
  }
  __syncthreads();
  if (t >= 32) return;
  int c = t;
  float ssq = 0.f;
  for (int ck = 0; ck < 32; ck++) ssq += qnp[((size_t)b*32 + ck)*CC + h*32 + c];
  float qn = fmaxf(sqrtf(ssq), 1e-12f);
  float rowS[32], rowP[32];
  #pragma unroll
  for (int d = 0; d < 32; d++){
    float sv = 0.f, pv = 0.f;
    for (int ck = 0; ck < 8; ck++){
      sv += Scfa[(size_t)(bh*8 + ck)*1024 + c*32 + d];
      pv += Spos[(size_t)(bh*8 + ck)*1024 + c*32 + d];
    }
    rowS[d] = sv; rowP[d] = pv;
  }
  float tv = temp[h];
  float m1 = -3e38f, m2 = -3e38f;
  #pragma unroll
  for (int d = 0; d < 32; d++){
    rowS[d] = rowS[d] / (qn*kn[d]) * tv;
    m1 = fmaxf(m1, rowS[d]);
    m2 = fmaxf(m2, rowP[d]);
  }
  float s1 = 0.f, s2 = 0.f;
  #pragma unroll
  for (int d = 0; d < 32; d++){
    rowS[d] = __expf(rowS[d] - m1); s1 += rowS[d];
    rowP[d] = __expf(rowP[d] - m2); s2 += rowP[d];
  }
  float r1 = 1.f/s1, r2 = 1.f/s2;
  #pragma unroll
  for (int d = 0; d < 32; d++)
    att[(size_t)bh*1024 + c*32 + d] = rowS[d]*r1 + rowP[d]*r2;
}

// ---------------- PV: outT[n][c] = sum_d att[c][d] * v[d][n] ----------------
__global__ __launch_bounds__(256)
void pv_k(const float* __restrict__ att, const unsigned short* __restrict__ vd, int stride,
          unsigned short* __restrict__ outT)
{
  __shared__ float As[32][33];
  int bh = blockIdx.x >> 8; int mc = blockIdx.x & 255;
  int b = bh / HEADS, h = bh - b*HEADS;
  int t = threadIdx.x;
  for (int i = t; i < 1024; i += 256) As[i >> 5][i & 31] = att[(size_t)bh*1024 + i];
  __syncthreads();
  int gm = b*NPIX + mc*64 + (t >> 2);
  int cq = t & 3;
  const unsigned short* vp = vd + (size_t)gm*stride + h*32;
  float acc[8] = {0,0,0,0,0,0,0,0};
  for (int d = 0; d < 32; d++){
    float vv = b2f(vp[d]);
    #pragma unroll
    for (int j = 0; j < 8; j++) acc[j] += As[cq*8 + j][d] * vv;
  }
  us8 o;
  #pragma unroll
  for (int j = 0; j < 8; j++) o[j] = f2b(acc[j]);
  *(us8*)(outT + (size_t)gm*CC + h*32 + cq*8) = o;
}

// ---------------- weight prep ----------------
__global__ void castcopy_k(const float* __restrict__ s, unsigned short* __restrict__ d, int n){
  int i = blockIdx.x*256 + threadIdx.x; if (i < n) d[i] = f2b(s[i]);
}
// SEL-in W: [co][cib][s][ci64], cib=0..2 (C=192), chunk = cib*9+s
__global__ void prepselin_k(const float* __restrict__ s, unsigned short* __restrict__ d){
  int i = blockIdx.x*256 + threadIdx.x;
  if (i >= 510*1728) return;
  int co = i / 1728, rem = i - co*1728;
  int chunk = rem >> 6, e = rem & 63;
  int cib = chunk / 9, sl = chunk - cib*9;
  int ci = cib*64 + e;
  d[i] = f2b(s[(size_t)(co*192 + ci)*9 + sl]);
}
// SEL-out W: [co][cib][s][ci64], cib=0..7 (C=512 padded), chunk = cib*9+s
__global__ void prepselout_k(const float* __restrict__ s, unsigned short* __restrict__ d){
  int i = blockIdx.x*256 + threadIdx.x;
  if (i >= 192*4608) return;
  int co = i / 4608, rem = i - co*4608;
  int chunk = rem >> 6, e = rem & 63;
  int cib = chunk / 9, sl = chunk - cib*9;
  int ci = cib*64 + e;
  d[i] = (ci < 510) ? f2b(s[(size_t)(co*510 + ci)*9 + sl]) : (unsigned short)0;
}
// bias for combined 960-col GEMM: cols 0..383 = pos_embed projections, rest 0
__global__ void prepbias_k(const float* __restrict__ pq, const float* __restrict__ pk,
                           const float* __restrict__ pe, float* __restrict__ bias){
  int r = blockIdx.x*64 + threadIdx.x;
  if (r >= 960) return;
  float s = 0.f;
  if (r < 384){
    const float* Wp = (r < 192) ? pq : pk;
    int co = (r < 192) ? r : r - 192;
    for (int ci = 0; ci < 192; ci++) s += Wp[co*192 + ci]*pe[ci];
  }
  bias[r] = s;
}
// dw weights -> [s][c] transposed layouts (qkv fused 576; sel padded 512)
__global__ void prepdwT_k(const float* __restrict__ qdw, const float* __restrict__ kvdw,
                          const float* __restrict__ seldw,
                          float* __restrict__ wqkv, float* __restrict__ wsel){
  int i = blockIdx.x*256 + threadIdx.x;
  if (i < 9*576){
    int s = i / 576, c = i - s*576;
    wqkv[i] = (c < 192) ? qdw[c*9 + s] : kvdw[(size_t)(c-192)*9 + s];
  }
  int j = i - 9*576;
  if (j >= 0 && j < 9*512){
    int s = j / 512, c = j - s*512;
    wsel[j] = (c < 510) ? seldw[(size_t)c*9 + s] : 0.f;
  }
}

// ---------------- launch ----------------
extern "C" void kernel_launch(void* const* d_in, const int* in_sizes, int n_in,
                              void* d_out, int out_size, void* d_ws, size_t ws_size,
                              hipStream_t stream)
{
  const float* x       = (const float*)d_in[0];
  const float* ln_w    = (const float*)d_in[1];
  const float* ln_b    = (const float*)d_in[2];
  const float* temp    = (const float*)d_in[3];
  const float* q_w     = (const float*)d_in[4];
  const float* q_dw    = (const float*)d_in[5];
  const float* kv_w    = (const float*)d_in[6];
  const float* kv_dw   = (const float*)d_in[7];
  const float* proj_w  = (const float*)d_in[8];
  const float* pos_e   = (const float*)d_in[9];
  const float* posq_w  = (const float*)d_in[10];
  const float* posk_w  = (const float*)d_in[11];
  const float* selin_w = (const float*)d_in[12];
  const float* seldw_w = (const float*)d_in[13];
  const float* selout_w= (const float*)d_in[14];
  const float* alphaP  = (const float*)d_in[15];

  char* ws = (char*)d_ws;
  unsigned short* zerop  = (unsigned short*)(ws + 0);         // 4KB zeros
  float* biasC           = (float*)(ws + 4096);               // 960 f32
  float* Spos            = (float*)(ws + 8192);               // 24*8*1024 f32
  float* Scfa            = (float*)(ws + 794624);
  float* qnp             = (float*)(ws + 1581056);            // 4*32*192 f32
  float* knp             = (float*)(ws + 1679360);
  float* att             = (float*)(ws + 1777664);            // 24*1024 f32
  unsigned short* WC     = (unsigned short*)(ws + 2097152);   // 960x192 bf16 (posq,posk,q,kv)
  unsigned short* Wproj  = (unsigned short*)(ws + 2465792);   // 192x192
  unsigned short* Wselin = (unsigned short*)(ws + 2539520);   // 510x1728
  unsigned short* Wselout= (unsigned short*)(ws + 4302080);   // 192x4608
  float* WdwQKV          = (float*)(ws + 6071552);            // 9x576 f32
  float* WdwSEL          = (float*)(ws + 6092288);            // 9x512 f32
  // big regions (sequenced reuse)
  unsigned short* normx  = (unsigned short*)(ws + 8388608);   // A: normx -> outT (25.2MB)
  unsigned short* outT   = normx;
  unsigned short* qp     = (unsigned short*)(ws + 33554432);  // B: qp(126MB) -> x2(50.3) + nx/g2
  float*          x2     = (float*)(ws + 33554432);
  unsigned short* nx     = (unsigned short*)(ws + 83886080);
  unsigned short* g2     = (unsigned short*)(ws + 83886080);
  unsigned short* qkvd   = (unsigned short*)(ws + 159383552); // C: qkvd(75.5MB) -> g(67MB)
  unsigned short* g      = qkvd;

  hipMemsetAsync(zerop, 0, 4096, stream);

  // weight prep
  castcopy_k<<<144, 256, 0, stream>>>(posq_w, WC,          36864);
  castcopy_k<<<144, 256, 0, stream>>>(posk_w, WC + 36864,  36864);
  castcopy_k<<<144, 256, 0, stream>>>(q_w,    WC + 73728,  36864);
  castcopy_k<<<288, 256, 0, stream>>>(kv_w,   WC + 110592, 73728);
  castcopy_k<<<144, 256, 0, stream>>>(proj_w, Wproj,       36864);
  prepselin_k<<<3443, 256, 0, stream>>>(selin_w, Wselin);
  prepselout_k<<<3456, 256, 0, stream>>>(selout_w, Wselout);
  prepbias_k<<<15, 64, 0, stream>>>(posq_w, posk_w, pos_e, biasC);
  prepdwT_k<<<39, 256, 0, stream>>>(q_dw, kv_dw, seldw_w, WdwQKV, WdwSEL);

  // LN1
  ln1_k<<<1024, 256, 0, stream>>>(x, ln_w, ln_b, normx);
  // combined pos_q/pos_k/q/kv GEMM (960 cols, bias on first 384)
  gemm_k<0,1><<<512*8, 256, 0, stream>>>(normx, 192, WC, 192, 192, 960, 960, 960, 8,
                                         qp, biasC, nullptr, nullptr, nullptr, zerop);
  // pos logits
  pairdot_k<<<192, 256, 0, stream>>>(qp, qp + 192, 960, Spos);
  // fused depthwise q,k,v -> qkvd (n,576)
  dw_k<72,0><<<18432, 256, 0, stream>>>(qp + 384, 960, WdwQKV, 576, qkvd, 576);
  // l2 norms (partials)
  sumsq_k<<<128, 192, 0, stream>>>(qkvd,       576, qnp);
  sumsq_k<<<128, 192, 0, stream>>>(qkvd + 192, 576, knp);
  // cfa logits
  pairdot_k<<<192, 256, 0, stream>>>(qkvd, qkvd + 192, 576, Scfa);
  // softmaxes + combine
  smax_k<<<24, 64, 0, stream>>>(Spos, Scfa, qnp, knp, temp, att);
  // PV
  pv_k<<<24*256, 256, 0, stream>>>(att, qkvd + 384, 576, outT);
  // proj + residual -> x2 (f32, (n,c))
  gemm_k<1,1><<<512*2, 256, 0, stream>>>(outT, 192, Wproj, 192, 192, 192, 192, 0, 2,
                                         nullptr, nullptr, x, x2, alphaP, zerop);
  // LN2
  ln2_k<<<16384, 256, 0, stream>>>(x2, ln_w, ln_b, nx);
  // SEL in conv3x3 (implicit GEMM, K=1728, slice-inner order)
  gemm_k<0,9><<<512*4, 256, 0, stream>>>(nx, 192, Wselin, 1728, 192, 510, 512, 512, 4,
                                         g, nullptr, nullptr, nullptr, nullptr, zerop);
  // SEL depthwise + SiLU
  dw_k<64,1><<<16384, 256, 0, stream>>>(g, 512, WdwSEL, 512, g2, 512);
  // SEL out conv3x3 (K=4608, slice-inner order) + final residual -> d_out NCHW
  gemm_k<2,9><<<512*2, 256, 0, stream>>>(g2, 512, Wselout, 4608, 512, 192, 192, 0, 2,
                                         nullptr, nullptr, x2, (float*)d_out, alphaP, zerop);
}

// Round 5
// 878.513 us; speedup vs baseline: 2.1914x; 1.0695x over previous
//
#include <hip/hip_runtime.h>
#include <hip/hip_bf16.h>
#include <stdint.h>

#define DEVI __device__ __forceinline__

typedef __attribute__((ext_vector_type(8))) unsigned short us8;
typedef __attribute__((ext_vector_type(8))) __bf16 bf16x8;
typedef __attribute__((ext_vector_type(4))) float f32x4;

#define BB 4
#define CC 192
#define HH 128
#define NPIX 16384
#define MTOT 65536
#define HEADS 6

DEVI float b2f(unsigned short u){ return __uint_as_float(((unsigned)u)<<16); }
DEVI unsigned short f2b(float f){
  unsigned u = __float_as_uint(f);
  return (unsigned short)((u + 0x7fffu + ((u>>16)&1u)) >> 16);
}

DEVI void gload16(const void* g, void* l){
  __builtin_amdgcn_global_load_lds((const __attribute__((address_space(1))) unsigned int*)g,
                                   (__attribute__((address_space(3))) unsigned int*)l,
                                   16, 0, 0);
}

// ---------------- LayerNorm 1: x NCHW f32 -> norm_x (n,c) bf16 ----------------
__global__ __launch_bounds__(256)
void ln1_k(const float* __restrict__ x, const float* __restrict__ lnw,
           const float* __restrict__ lnb, unsigned short* __restrict__ nx)
{
  __shared__ float tile[CC*65];
  __shared__ float stats[64*2];
  int gbase = blockIdx.x * 64;            // global (b*NPIX+n) base
  int b = gbase >> 14; int n0 = gbase & (NPIX-1);
  for (int idx = threadIdx.x; idx < CC*64; idx += 256){
    int c = idx >> 6, j = idx & 63;
    tile[c*65 + j] = x[((size_t)b*CC + c)*NPIX + n0 + j];
  }
  __syncthreads();
  if (threadIdx.x < 64){
    int j = threadIdx.x;
    float s = 0.f, ss = 0.f;
    for (int c = 0; c < CC; c++){ float v = tile[c*65 + j]; s += v; ss += v*v; }
    float mu = s * (1.f/CC);
    float var = ss * (1.f/CC) - mu*mu;
    stats[j*2] = mu; stats[j*2+1] = rsqrtf(var + 1e-6f);
  }
  __syncthreads();
  for (int idx = threadIdx.x; idx < CC*64; idx += 256){
    int c = idx % CC, j = idx / CC;
    float v = (tile[c*65 + j] - stats[j*2]) * stats[j*2+1] * lnw[c] + lnb[c];
    nx[(size_t)(gbase + j)*CC + c] = f2b(v);
  }
}

// ---------------- LayerNorm 2: x2 (n,c) f32 -> nx (n,c) bf16 ----------------
__global__ __launch_bounds__(256)
void ln2_k(const float* __restrict__ x2, const float* __restrict__ lnw,
           const float* __restrict__ lnb, unsigned short* __restrict__ nx)
{
  int gm = blockIdx.x*4 + (threadIdx.x >> 6);
  int lane = threadIdx.x & 63;
  const float* row = x2 + (size_t)gm*CC;
  float v0 = row[lane], v1 = row[lane+64], v2 = row[lane+128];
  float s = v0+v1+v2, ss = v0*v0+v1*v1+v2*v2;
  #pragma unroll
  for (int o = 32; o >= 1; o >>= 1){
    s  += __shfl_xor(s,  o);
    ss += __shfl_xor(ss, o);
  }
  float mu = s * (1.f/CC);
  float rstd = rsqrtf(ss*(1.f/CC) - mu*mu + 1e-6f);
  unsigned short* o0 = nx + (size_t)gm*CC;
  o0[lane]     = f2b((v0-mu)*rstd*lnw[lane]     + lnb[lane]);
  o0[lane+64]  = f2b((v1-mu)*rstd*lnw[lane+64]  + lnb[lane+64]);
  o0[lane+128] = f2b((v2-mu)*rstd*lnw[lane+128] + lnb[lane+128]);
}

// ======== 256x256 8-wave double-buffered pipelined GEMM (T1+T2+T3min+T5) ========
// Out[m][co] = sum_k A[m][k]*W[co][k]; A (n,c) bf16 stride strideA; W [co][Ktot].
// NSLICES=9: implicit 3x3 conv, K-chunk t -> (cib=t/9, s=t%9), slice-inner order.
// EPI 0: store bf16; EPI 2: d_out NCHW f32 = res(n,c) + (1-alpha)*acc.
template<int EPI, int NSLICES>
__global__ __launch_bounds__(512, 2)
void gemm256_k(const unsigned short* __restrict__ A, int strideA,
               const unsigned short* __restrict__ W, int Ktot,
               int NcolsW, int NcolsStore, int outStride, int colBlocks,
               unsigned short* __restrict__ outB,
               const float* __restrict__ res, float* __restrict__ outF,
               const float* __restrict__ alphaP,
               const unsigned short* __restrict__ zerop)
{
  __shared__ unsigned short lds[65536];   // 128 KiB: A[2][256][64] then B[2][256][64]

  const int tid = threadIdx.x;
  const int l  = tid & 63;
  const int w  = tid >> 6;
  const int wm = w >> 2;        // 0..1  (M half)
  const int wn = w & 3;         // 0..3  (N quarter)

  // XCD-chunked bijective swizzle (grid % 8 == 0)
  const int q8 = gridDim.x >> 3;
  const int bid = (blockIdx.x & 7)*q8 + (blockIdx.x >> 3);
  const int mblk = bid / colBlocks;
  const int nblk = bid - mblk*colBlocks;
  const int m0 = mblk*256, co0 = nblk*256;

  // ---- staging geometry: instr i in 0..3, row = (w*4+i)*8 + (l>>3), slot = l&7
  int rowT[4], slotX[4];
  #pragma unroll
  for (int i = 0; i < 4; i++){
    rowT[i]  = (w*4 + i)*8 + (l >> 3);
    slotX[i] = (l & 7) ^ (rowT[i] & 7);
  }
  // A per-row statics
  const unsigned short* baseA[4];
  int hhA[4], wwA[4];
  #pragma unroll
  for (int i = 0; i < 4; i++){
    int gm = m0 + rowT[i];
    int np = gm & (NPIX-1);
    hhA[i] = np >> 7; wwA[i] = np & 127;
    baseA[i] = A + (size_t)gm*strideA + (slotX[i] << 3);
  }
  // B per-row statics
  const unsigned short* baseB[4];
  bool bval[4];
  #pragma unroll
  for (int i = 0; i < 4; i++){
    int co = co0 + rowT[i];
    bval[i] = (co < NcolsW);
    baseB[i] = bval[i] ? (W + (size_t)co*Ktot + (slotX[i] << 3)) : (zerop + (l << 3));
  }

  const int NT = Ktot >> 6;

  auto STAGE = [&](int ts){
    int buf = ts & 1;
    unsigned short* la = lds + buf*16384;
    unsigned short* lb = lds + 32768 + buf*16384;
    int ci0, dy = 0, dx = 0;
    if constexpr (NSLICES == 1){ ci0 = ts << 6; }
    else { int cib = ts/9, s = ts - cib*9; ci0 = cib << 6; dy = s/3 - 1; dx = s - (s/3)*3 - 1; }
    #pragma unroll
    for (int i = 0; i < 4; i++){
      const unsigned short* srcA;
      if constexpr (NSLICES == 1){
        srcA = baseA[i] + ci0;
      } else {
        int h2 = hhA[i] + dy, w2 = wwA[i] + dx;
        srcA = ((unsigned)h2 < 128u && (unsigned)w2 < 128u)
             ? (baseA[i] + (dy*HH + dx)*strideA + ci0)
             : (zerop + (l << 3));
      }
      gload16(srcA, la + (w*4 + i)*512);
    }
    #pragma unroll
    for (int i = 0; i < 4; i++){
      const unsigned short* srcB = bval[i] ? (baseB[i] + (ts << 6)) : baseB[i];
      gload16(srcB, lb + (w*4 + i)*512);
    }
  };

  f32x4 acc[8][4] = {};

  STAGE(0);
  asm volatile("s_waitcnt vmcnt(0)" ::: "memory");
  __syncthreads();

  for (int t = 0; t < NT; ++t){
    if (t + 1 < NT) STAGE(t + 1);
    const unsigned short* la = lds + (t & 1)*16384;
    const unsigned short* lb = lds + 32768 + (t & 1)*16384;
    __builtin_amdgcn_s_setprio(1);
    #pragma unroll
    for (int kk = 0; kk < 2; kk++){
      int ks = kk*4 + (l >> 4);
      bf16x8 bf[4];
      #pragma unroll
      for (int nf = 0; nf < 4; nf++){
        int rb = wn*64 + nf*16 + (l & 15);
        bf[nf] = *(const bf16x8*)(lb + rb*64 + ((ks ^ (rb & 7)) << 3));
      }
      #pragma unroll
      for (int mf = 0; mf < 8; mf++){
        int rm = wm*128 + mf*16 + (l & 15);
        bf16x8 af = *(const bf16x8*)(la + rm*64 + ((ks ^ (rm & 7)) << 3));
        #pragma unroll
        for (int nf = 0; nf < 4; nf++)
          acc[mf][nf] = __builtin_amdgcn_mfma_f32_16x16x32_bf16(af, bf[nf], acc[mf][nf], 0, 0, 0);
      }
    }
    __builtin_amdgcn_s_setprio(0);
    __syncthreads();   // implicit full drain (vmcnt+lgkm) = the one wait per K-step
  }

  float alpha = (EPI == 2) ? (1.f - *alphaP) : 0.f;
  #pragma unroll
  for (int mf = 0; mf < 8; mf++){
    int r0 = m0 + wm*128 + mf*16 + ((l >> 4) << 2);
    #pragma unroll
    for (int nf = 0; nf < 4; nf++){
      int co = co0 + wn*64 + nf*16 + (l & 15);
      if (co < NcolsStore){
        #pragma unroll
        for (int r = 0; r < 4; r++){
          int gm = r0 + r;
          float v = acc[mf][nf][r];
          if constexpr (EPI == 0){
            outB[(size_t)gm*outStride + co] = f2b(v);
          } else {
            int b = gm >> 14, np = gm & (NPIX-1);
            outF[((size_t)b*CC + co)*NPIX + np] = res[(size_t)gm*CC + co] + alpha*v;
          }
        }
      }
    }
  }
}

// ---------------- MFMA GEMM 128x128 (kept for K=192 GEMMs) ----------------
template<int EPI, int NSLICES>
__global__ __launch_bounds__(256, 2)
void gemm_k(const unsigned short* __restrict__ A, int strideA,
            const unsigned short* __restrict__ W, int Ktot, int sliceC,
            int NcolsW, int NcolsStore, int outStride, int colBlocks,
            unsigned short* __restrict__ outB,
            const float* __restrict__ bias,
            const float* __restrict__ res,
            float* __restrict__ outF,
            const float* __restrict__ alphaP,
            const unsigned short* __restrict__ zerop)
{
  __shared__ unsigned short lds[2*128*64];
  unsigned short* ldsA = lds;
  unsigned short* ldsB = lds + 128*64;

  const int tid = threadIdx.x;
  const int lane = tid & 63;
  const int wv = tid >> 6;
  const int q8 = gridDim.x >> 3;
  const int bid = (blockIdx.x & 7)*q8 + (blockIdx.x >> 3);
  const int mblk = bid / colBlocks;
  const int nblk = bid - mblk*colBlocks;
  const int m0 = mblk*128, co0 = nblk*128;

  const int jT = lane & 7;
  int rowT[4];
  #pragma unroll
  for (int i = 0; i < 4; i++) rowT[i] = ((wv*4 + i)*64 + lane) >> 3;

  const unsigned short* bsrc[4];
  #pragma unroll
  for (int i = 0; i < 4; i++){
    int co = co0 + rowT[i];
    int jj = jT ^ (rowT[i] & 7);
    bsrc[i] = (co < NcolsW) ? (W + (size_t)co*Ktot + (jj << 3))
                            : (zerop + (lane << 3));
  }

  const unsigned short* asrc[4];
  int gmA[4], jjA[4];
  #pragma unroll
  for (int i = 0; i < 4; i++){
    gmA[i] = m0 + rowT[i];
    jjA[i] = jT ^ (rowT[i] & 7);
    asrc[i] = A + (size_t)gmA[i]*strideA + (jjA[i] << 3);
  }

  f32x4 acc[4][4] = {};
  int ci0 = 0, s = 0, dy = -1, dx = -1;

  for (int k0 = 0; k0 < Ktot; k0 += 64){
    if constexpr (NSLICES == 1){
      #pragma unroll
      for (int i = 0; i < 4; i++){
        gload16(asrc[i], (char*)ldsA + (wv*4 + i)*1024);
        asrc[i] += 64;
      }
    } else {
      #pragma unroll
      for (int i = 0; i < 4; i++){
        int gm = gmA[i];
        int np = gm & (NPIX-1);
        int hh = np >> 7, ww = np & 127;
        int h2 = hh + dy, w2 = ww + dx;
        const unsigned short* src = ((unsigned)h2 < 128u && (unsigned)w2 < 128u)
          ? (A + (size_t)(gm + dy*HH + dx)*strideA + ci0 + (jjA[i] << 3))
          : (zerop + (lane << 3));
        gload16(src, (char*)ldsA + (wv*4 + i)*1024);
      }
    }
    #pragma unroll
    for (int i = 0; i < 4; i++){
      gload16(bsrc[i], (char*)ldsB + (wv*4 + i)*1024);
      bsrc[i] += 64;
    }
    asm volatile("s_waitcnt vmcnt(0)" ::: "memory");
    __syncthreads();

    #pragma unroll
    for (int kk = 0; kk < 2; kk++){
      bf16x8 af[4], bfr[4];
      int kb = kk*64 + ((lane >> 4) << 4);
      #pragma unroll
      for (int mi = 0; mi < 4; mi++){
        int rm = (wv >> 1)*64 + mi*16 + (lane & 15);
        int off = rm*128 + (kb ^ ((rm & 7) << 4));
        af[mi] = *(const bf16x8*)((const char*)ldsA + off);
      }
      #pragma unroll
      for (int ni = 0; ni < 4; ni++){
        int rb = (wv & 1)*64 + ni*16 + (lane & 15);
        int off = rb*128 + (kb ^ ((rb & 7) << 4));
        bfr[ni] = *(const bf16x8*)((const char*)ldsB + off);
      }
      #pragma unroll
      for (int mi = 0; mi < 4; mi++)
        #pragma unroll
        for (int ni = 0; ni < 4; ni++)
          acc[mi][ni] = __builtin_amdgcn_mfma_f32_16x16x32_bf16(af[mi], bfr[ni], acc[mi][ni], 0, 0, 0);
    }
    __syncthreads();

    if constexpr (NSLICES > 1){
      s++; if (s == 9){ s = 0; ci0 += 64; }
      dy = s/3 - 1; dx = s - (s/3)*3 - 1;
    }
  }
  (void)sliceC;

  float alpha = 0.f;
  if (EPI == 1) alpha = *alphaP;
  if (EPI == 2) alpha = 1.f - *alphaP;
  const int colb = co0 + (wv & 1)*64;
  const int rowb = m0 + (wv >> 1)*64;
  #pragma unroll
  for (int mi = 0; mi < 4; mi++){
    int r0 = rowb + mi*16 + ((lane >> 4) << 2);
    #pragma unroll
    for (int ni = 0; ni < 4; ni++){
      int co = colb + ni*16 + (lane & 15);
      if (co < NcolsStore){
        float bv = (EPI == 0 && bias) ? bias[co] : 0.f;
        #pragma unroll
        for (int r = 0; r < 4; r++){
          int gm = r0 + r;
          float v = acc[mi][ni][r];
          if constexpr (EPI == 0){
            outB[(size_t)gm*outStride + co] = f2b(v + bv);
          } else if constexpr (EPI == 1){
            int b = gm >> 14, np = gm & (NPIX-1);
            outF[(size_t)gm*CC + co] = res[((size_t)b*CC + co)*NPIX + np] + alpha*v;
          } else {
            int b = gm >> 14, np = gm & (NPIX-1);
            outF[((size_t)b*CC + co)*NPIX + np] = res[(size_t)gm*CC + co] + alpha*v;
          }
        }
      }
    }
  }
}

// ---------------- Depthwise 3x3 (+optional SiLU), (n,c) bf16, [s][c] weights ----------------
template<int NCHV, int DOSILU>
__global__ __launch_bounds__(256)
void dw_k(const unsigned short* __restrict__ src, int strideS,
          const float* __restrict__ wtT, int wstride,
          unsigned short* __restrict__ dst, int strideD)
{
  const int q8 = gridDim.x >> 3;
  const int bid = (blockIdx.x & 7)*q8 + (blockIdx.x >> 3);
  int idx = bid*256 + threadIdx.x;
  int gm = idx / NCHV;
  int cb = idx - gm*NCHV;
  int c = cb*8;
  int np = gm & (NPIX-1);
  int hh = np >> 7, ww = np & 127;
  float acc[8] = {0,0,0,0,0,0,0,0};
  #pragma unroll
  for (int s = 0; s < 9; s++){
    int dy = s/3 - 1, dx = s%3 - 1;
    int h2 = hh + dy, w2 = ww + dx;
    if ((unsigned)h2 < 128u && (unsigned)w2 < 128u){
      us8 t = *(const us8*)(src + (size_t)(gm + dy*HH + dx)*strideS + c);
      f32x4 w0 = *(const f32x4*)(wtT + s*wstride + c);
      f32x4 w1 = *(const f32x4*)(wtT + s*wstride + c + 4);
      #pragma unroll
      for (int j = 0; j < 4; j++){
        acc[j]   += b2f(t[j])   * w0[j];
        acc[4+j] += b2f(t[4+j]) * w1[j];
      }
    }
  }
  us8 o;
  #pragma unroll
  for (int j = 0; j < 8; j++){
    float v = acc[j];
    if (DOSILU) v = v / (1.f + __expf(-v));
    o[j] = f2b(v);
  }
  *(us8*)(dst + (size_t)gm*strideD + c) = o;
}

// ---------------- per-(b,c) sum of squares over n (partials) ----------------
__global__ __launch_bounds__(192)
void sumsq_k(const unsigned short* __restrict__ q, int stride, float* __restrict__ part)
{
  int b = blockIdx.x >> 5, ch = blockIdx.x & 31;
  int c = threadIdx.x;
  const unsigned short* base = q + ((size_t)b*NPIX + ch*512)*stride + c;
  float acc = 0.f;
  for (int r = 0; r < 512; r++){ float v = b2f(base[(size_t)r*stride]); acc += v*v; }
  part[(size_t)(b*32 + ch)*CC + c] = acc;
}

// ---------------- QK^T partials: S[c][d] = sum_n q[c,n]k[d,n] ----------------
__global__ __launch_bounds__(256)
void pairdot_k(const unsigned short* __restrict__ qb, const unsigned short* __restrict__ kb,
               int stride, float* __restrict__ Spart)
{
  __shared__ float qs[32][129];
  __shared__ float ks[32][129];
  int bh = blockIdx.x >> 3;
  int chunk = blockIdx.x & 7;
  int b = bh / HEADS, h = bh - b*HEADS;
  int t = threadIdx.x;
  int cP = t >> 3;
  int dg = t & 7;
  size_t gm0 = (size_t)b*NPIX + chunk*2048;
  int r = t >> 1, hf = t & 1;
  float acc0=0, acc1=0, acc2=0, acc3=0;
  for (int sub = 0; sub < 16; sub++){
    __syncthreads();
    {
      const unsigned short* pq = qb + (gm0 + sub*128 + r)*stride + h*32 + hf*16;
      const unsigned short* pk = kb + (gm0 + sub*128 + r)*stride + h*32 + hf*16;
      us8 a0 = *(const us8*)pq; us8 a1 = *(const us8*)(pq + 8);
      us8 b0 = *(const us8*)pk; us8 b1 = *(const us8*)(pk + 8);
      #pragma unroll
      for (int j = 0; j < 8; j++){
        qs[hf*16 + j][r]     = b2f(a0[j]);
        qs[hf*16 + 8 + j][r] = b2f(a1[j]);
        ks[hf*16 + j][r]     = b2f(b0[j]);
        ks[hf*16 + 8 + j][r] = b2f(b1[j]);
      }
    }
    __syncthreads();
    for (int n = 0; n < 128; n++){
      float qv = qs[cP][n];
      acc0 += qv * ks[dg*4+0][n];
      acc1 += qv * ks[dg*4+1][n];
      acc2 += qv * ks[dg*4+2][n];
      acc3 += qv * ks[dg*4+3][n];
    }
  }
  float* o = Spart + (size_t)blockIdx.x*1024 + cP*32 + dg*4;
  o[0]=acc0; o[1]=acc1; o[2]=acc2; o[3]=acc3;
}

// ---------------- softmax(cfa)+softmax(pos) combine ----------------
__global__ __launch_bounds__(64)
void smax_k(const float* __restrict__ Spos, const float* __restrict__ Scfa,
            const float* __restrict__ qnp, const float* __restrict__ knp,
            const float* __restrict__ temp, float* __restrict__ att)
{
  int bh = blockIdx.x; int b = bh / HEADS, h = bh - b*HEADS;
  __shared__ float kn[32];
  int t = threadIdx.x;
  if (t < 32){
    float ss = 0.f;
    for (int ck = 0; ck < 32; ck++) ss += knp[((size_t)b*32 + ck)*CC + h*32 + t];
    kn[t] = fmaxf(sqrtf(ss), 1e-12f);
  }
  __syncthreads();
  if (t >= 32) return;
  int c = t;
  float ssq = 0.f;
  for (int ck = 0; ck < 32; ck++) ssq += qnp[((size_t)b*32 + ck)*CC + h*32 + c];
  float qn = fmaxf(sqrtf(ssq), 1e-12f);
  float rowS[32], rowP[32];
  #pragma unroll
  for (int d = 0; d < 32; d++){
    float sv = 0.f, pv = 0.f;
    for (int ck = 0; ck < 8; ck++){
      sv += Scfa[(size_t)(bh*8 + ck)*1024 + c*32 + d];
      pv += Spos[(size_t)(bh*8 + ck)*1024 + c*32 + d];
    }
    rowS[d] = sv; rowP[d] = pv;
  }
  float tv = temp[h];
  float m1 = -3e38f, m2 = -3e38f;
  #pragma unroll
  for (int d = 0; d < 32; d++){
    rowS[d] = rowS[d] / (qn*kn[d]) * tv;
    m1 = fmaxf(m1, rowS[d]);
    m2 = fmaxf(m2, rowP[d]);
  }
  float s1 = 0.f, s2 = 0.f;
  #pragma unroll
  for (int d = 0; d < 32; d++){
    rowS[d] = __expf(rowS[d] - m1); s1 += rowS[d];
    rowP[d] = __expf(rowP[d] - m2); s2 += rowP[d];
  }
  float r1 = 1.f/s1, r2 = 1.f/s2;
  #pragma unroll
  for (int d = 0; d < 32; d++)
    att[(size_t)bh*1024 + c*32 + d] = rowS[d]*r1 + rowP[d]*r2;
}

// ---------------- PV: outT[n][c] = sum_d att[c][d] * v[d][n] ----------------
__global__ __launch_bounds__(256)
void pv_k(const float* __restrict__ att, const unsigned short* __restrict__ vd, int stride,
          unsigned short* __restrict__ outT)
{
  __shared__ float As[32][33];
  int bh = blockIdx.x >> 8; int mc = blockIdx.x & 255;
  int b = bh / HEADS, h = bh - b*HEADS;
  int t = threadIdx.x;
  for (int i = t; i < 1024; i += 256) As[i >> 5][i & 31] = att[(size_t)bh*1024 + i];
  __syncthreads();
  int gm = b*NPIX + mc*64 + (t >> 2);
  int cq = t & 3;
  const unsigned short* vp = vd + (size_t)gm*stride + h*32;
  float acc[8] = {0,0,0,0,0,0,0,0};
  for (int d = 0; d < 32; d++){
    float vv = b2f(vp[d]);
    #pragma unroll
    for (int j = 0; j < 8; j++) acc[j] += As[cq*8 + j][d] * vv;
  }
  us8 o;
  #pragma unroll
  for (int j = 0; j < 8; j++) o[j] = f2b(acc[j]);
  *(us8*)(outT + (size_t)gm*CC + h*32 + cq*8) = o;
}

// ---------------- weight prep ----------------
__global__ void castcopy_k(const float* __restrict__ s, unsigned short* __restrict__ d, int n){
  int i = blockIdx.x*256 + threadIdx.x; if (i < n) d[i] = f2b(s[i]);
}
// SEL-in W: [co][cib][s][ci64], cib=0..2 (C=192), chunk = cib*9+s
__global__ void prepselin_k(const float* __restrict__ s, unsigned short* __restrict__ d){
  int i = blockIdx.x*256 + threadIdx.x;
  if (i >= 510*1728) return;
  int co = i / 1728, rem = i - co*1728;
  int chunk = rem >> 6, e = rem & 63;
  int cib = chunk / 9, sl = chunk - cib*9;
  int ci = cib*64 + e;
  d[i] = f2b(s[(size_t)(co*192 + ci)*9 + sl]);
}
// SEL-out W: [co][cib][s][ci64], cib=0..7 (C=512 padded), chunk = cib*9+s
__global__ void prepselout_k(const float* __restrict__ s, unsigned short* __restrict__ d){
  int i = blockIdx.x*256 + threadIdx.x;
  if (i >= 192*4608) return;
  int co = i / 4608, rem = i - co*4608;
  int chunk = rem >> 6, e = rem & 63;
  int cib = chunk / 9, sl = chunk - cib*9;
  int ci = cib*64 + e;
  d[i] = (ci < 510) ? f2b(s[(size_t)(co*510 + ci)*9 + sl]) : (unsigned short)0;
}
// bias for combined 960-col GEMM: cols 0..383 = pos_embed projections, rest 0
__global__ void prepbias_k(const float* __restrict__ pq, const float* __restrict__ pk,
                           const float* __restrict__ pe, float* __restrict__ bias){
  int r = blockIdx.x*64 + threadIdx.x;
  if (r >= 960) return;
  float s = 0.f;
  if (r < 384){
    const float* Wp = (r < 192) ? pq : pk;
    int co = (r < 192) ? r : r - 192;
    for (int ci = 0; ci < 192; ci++) s += Wp[co*192 + ci]*pe[ci];
  }
  bias[r] = s;
}
// dw weights -> [s][c] transposed layouts (qkv fused 576; sel padded 512)
__global__ void prepdwT_k(const float* __restrict__ qdw, const float* __restrict__ kvdw,
                          const float* __restrict__ seldw,
                          float* __restrict__ wqkv, float* __restrict__ wsel){
  int i = blockIdx.x*256 + threadIdx.x;
  if (i < 9*576){
    int s = i / 576, c = i - s*576;
    wqkv[i] = (c < 192) ? qdw[c*9 + s] : kvdw[(size_t)(c-192)*9 + s];
  }
  int j = i - 9*576;
  if (j >= 0 && j < 9*512){
    int s = j / 512, c = j - s*512;
    wsel[j] = (c < 510) ? seldw[(size_t)c*9 + s] : 0.f;
  }
}

// ---------------- launch ----------------
extern "C" void kernel_launch(void* const* d_in, const int* in_sizes, int n_in,
                              void* d_out, int out_size, void* d_ws, size_t ws_size,
                              hipStream_t stream)
{
  const float* x       = (const float*)d_in[0];
  const float* ln_w    = (const float*)d_in[1];
  const float* ln_b    = (const float*)d_in[2];
  const float* temp    = (const float*)d_in[3];
  const float* q_w     = (const float*)d_in[4];
  const float* q_dw    = (const float*)d_in[5];
  const float* kv_w    = (const float*)d_in[6];
  const float* kv_dw   = (const float*)d_in[7];
  const float* proj_w  = (const float*)d_in[8];
  const float* pos_e   = (const float*)d_in[9];
  const float* posq_w  = (const float*)d_in[10];
  const float* posk_w  = (const float*)d_in[11];
  const float* selin_w = (const float*)d_in[12];
  const float* seldw_w = (const float*)d_in[13];
  const float* selout_w= (const float*)d_in[14];
  const float* alphaP  = (const float*)d_in[15];

  char* ws = (char*)d_ws;
  unsigned short* zerop  = (unsigned short*)(ws + 0);         // 4KB zeros
  float* biasC           = (float*)(ws + 4096);               // 960 f32
  float* Spos            = (float*)(ws + 8192);               // 24*8*1024 f32
  float* Scfa            = (float*)(ws + 794624);
  float* qnp             = (float*)(ws + 1581056);            // 4*32*192 f32
  float* knp             = (float*)(ws + 1679360);
  float* att             = (float*)(ws + 1777664);            // 24*1024 f32
  unsigned short* WC     = (unsigned short*)(ws + 2097152);   // 960x192 bf16 (posq,posk,q,kv)
  unsigned short* Wproj  = (unsigned short*)(ws + 2465792);   // 192x192
  unsigned short* Wselin = (unsigned short*)(ws + 2539520);   // 510x1728
  unsigned short* Wselout= (unsigned short*)(ws + 4302080);   // 192x4608
  float* WdwQKV          = (float*)(ws + 6071552);            // 9x576 f32
  float* WdwSEL          = (float*)(ws + 6092288);            // 9x512 f32
  // big regions (sequenced reuse)
  unsigned short* normx  = (unsigned short*)(ws + 8388608);   // A: normx -> outT (25.2MB)
  unsigned short* outT   = normx;
  unsigned short* qp     = (unsigned short*)(ws + 33554432);  // B: qp(126MB) -> x2(50.3) + nx/g2
  float*          x2     = (float*)(ws + 33554432);
  unsigned short* nx     = (unsigned short*)(ws + 83886080);
  unsigned short* g2     = (unsigned short*)(ws + 83886080);
  unsigned short* qkvd   = (unsigned short*)(ws + 159383552); // C: qkvd(75.5MB) -> g(67MB)
  unsigned short* g      = qkvd;

  hipMemsetAsync(zerop, 0, 4096, stream);

  // weight prep
  castcopy_k<<<144, 256, 0, stream>>>(posq_w, WC,          36864);
  castcopy_k<<<144, 256, 0, stream>>>(posk_w, WC + 36864,  36864);
  castcopy_k<<<144, 256, 0, stream>>>(q_w,    WC + 73728,  36864);
  castcopy_k<<<288, 256, 0, stream>>>(kv_w,   WC + 110592, 73728);
  castcopy_k<<<144, 256, 0, stream>>>(proj_w, Wproj,       36864);
  prepselin_k<<<3443, 256, 0, stream>>>(selin_w, Wselin);
  prepselout_k<<<3456, 256, 0, stream>>>(selout_w, Wselout);
  prepbias_k<<<15, 64, 0, stream>>>(posq_w, posk_w, pos_e, biasC);
  prepdwT_k<<<39, 256, 0, stream>>>(q_dw, kv_dw, seldw_w, WdwQKV, WdwSEL);

  // LN1
  ln1_k<<<1024, 256, 0, stream>>>(x, ln_w, ln_b, normx);
  // combined pos_q/pos_k/q/kv GEMM (960 cols, bias on first 384)
  gemm_k<0,1><<<512*8, 256, 0, stream>>>(normx, 192, WC, 192, 192, 960, 960, 960, 8,
                                         qp, biasC, nullptr, nullptr, nullptr, zerop);
  // pos logits
  pairdot_k<<<192, 256, 0, stream>>>(qp, qp + 192, 960, Spos);
  // fused depthwise q,k,v -> qkvd (n,576)
  dw_k<72,0><<<18432, 256, 0, stream>>>(qp + 384, 960, WdwQKV, 576, qkvd, 576);
  // l2 norms (partials)
  sumsq_k<<<128, 192, 0, stream>>>(qkvd,       576, qnp);
  sumsq_k<<<128, 192, 0, stream>>>(qkvd + 192, 576, knp);
  // cfa logits
  pairdot_k<<<192, 256, 0, stream>>>(qkvd, qkvd + 192, 576, Scfa);
  // softmaxes + combine
  smax_k<<<24, 64, 0, stream>>>(Spos, Scfa, qnp, knp, temp, att);
  // PV
  pv_k<<<24*256, 256, 0, stream>>>(att, qkvd + 384, 576, outT);
  // proj + residual -> x2 (f32, (n,c))
  gemm_k<1,1><<<512*2, 256, 0, stream>>>(outT, 192, Wproj, 192, 192, 192, 192, 0, 2,
                                         nullptr, nullptr, x, x2, alphaP, zerop);
  // LN2
  ln2_k<<<16384, 256, 0, stream>>>(x2, ln_w, ln_b, nx);
  // SEL in conv3x3 (implicit GEMM, K=1728) — 256^2 pipelined
  gemm256_k<0,9><<<512, 512, 0, stream>>>(nx, 192, Wselin, 1728, 510, 512, 512, 2,
                                          g, nullptr, nullptr, alphaP, zerop);
  // SEL depthwise + SiLU
  dw_k<64,1><<<16384, 256, 0, stream>>>(g, 512, WdwSEL, 512, g2, 512);
  // SEL out conv3x3 (K=4608) + final residual -> d_out NCHW — 256^2 pipelined
  gemm256_k<2,9><<<256, 512, 0, stream>>>(g2, 512, Wselout, 4608, 192, 192, 0, 1,
                                          nullptr, x2, (float*)d_out, alphaP, zerop);
}

// Round 8
// 855.033 us; speedup vs baseline: 2.2516x; 1.0275x over previous
//
#include <hip/hip_runtime.h>
#include <hip/hip_bf16.h>
#include <stdint.h>

#define DEVI __device__ __forceinline__

typedef __attribute__((ext_vector_type(8))) unsigned short us8;
typedef __attribute__((ext_vector_type(4))) unsigned short us4;
typedef __attribute__((ext_vector_type(8))) __bf16 bf16x8;
typedef __attribute__((ext_vector_type(4))) float f32x4;

#define BB 4
#define CC 192
#define HH 128
#define NPIX 16384
#define MTOT 65536
#define HEADS 6

DEVI float b2f(unsigned short u){ return __uint_as_float(((unsigned)u)<<16); }
DEVI unsigned short f2b(float f){
  unsigned u = __float_as_uint(f);
  return (unsigned short)((u + 0x7fffu + ((u>>16)&1u)) >> 16);
}

DEVI void gload16(const void* g, void* l){
  __builtin_amdgcn_global_load_lds((const __attribute__((address_space(1))) unsigned int*)g,
                                   (__attribute__((address_space(3))) unsigned int*)l,
                                   16, 0, 0);
}

// ---------------- LayerNorm 1: x NCHW f32 -> norm_x (n,c) bf16 ----------------
__global__ __launch_bounds__(256)
void ln1_k(const float* __restrict__ x, const float* __restrict__ lnw,
           const float* __restrict__ lnb, unsigned short* __restrict__ nx)
{
  __shared__ float tile[CC*65];
  __shared__ float stats[64*2];
  int gbase = blockIdx.x * 64;            // global (b*NPIX+n) base
  int b = gbase >> 14; int n0 = gbase & (NPIX-1);
  for (int idx = threadIdx.x; idx < CC*64; idx += 256){
    int c = idx >> 6, j = idx & 63;
    tile[c*65 + j] = x[((size_t)b*CC + c)*NPIX + n0 + j];
  }
  __syncthreads();
  if (threadIdx.x < 64){
    int j = threadIdx.x;
    float s = 0.f, ss = 0.f;
    for (int c = 0; c < CC; c++){ float v = tile[c*65 + j]; s += v; ss += v*v; }
    float mu = s * (1.f/CC);
    float var = ss * (1.f/CC) - mu*mu;
    stats[j*2] = mu; stats[j*2+1] = rsqrtf(var + 1e-6f);
  }
  __syncthreads();
  for (int idx = threadIdx.x; idx < CC*64; idx += 256){
    int c = idx % CC, j = idx / CC;
    float v = (tile[c*65 + j] - stats[j*2]) * stats[j*2+1] * lnw[c] + lnb[c];
    nx[(size_t)(gbase + j)*CC + c] = f2b(v);
  }
}

// ---------------- LayerNorm 2: x2 (n,c) f32 -> nx (n,c) bf16 ----------------
__global__ __launch_bounds__(256)
void ln2_k(const float* __restrict__ x2, const float* __restrict__ lnw,
           const float* __restrict__ lnb, unsigned short* __restrict__ nx)
{
  int gm = blockIdx.x*4 + (threadIdx.x >> 6);
  int lane = threadIdx.x & 63;
  const float* row = x2 + (size_t)gm*CC;
  float v0 = row[lane], v1 = row[lane+64], v2 = row[lane+128];
  float s = v0+v1+v2, ss = v0*v0+v1*v1+v2*v2;
  #pragma unroll
  for (int o = 32; o >= 1; o >>= 1){
    s  += __shfl_xor(s,  o);
    ss += __shfl_xor(ss, o);
  }
  float mu = s * (1.f/CC);
  float rstd = rsqrtf(ss*(1.f/CC) - mu*mu + 1e-6f);
  unsigned short* o0 = nx + (size_t)gm*CC;
  o0[lane]     = f2b((v0-mu)*rstd*lnw[lane]     + lnb[lane]);
  o0[lane+64]  = f2b((v1-mu)*rstd*lnw[lane+64]  + lnb[lane+64]);
  o0[lane+128] = f2b((v2-mu)*rstd*lnw[lane+128] + lnb[lane+128]);
}

// ======== 256x256 8-wave dbuf GEMM with COUNTED vmcnt (T1+T2+T4+T5) ========
// Out[m][co] = sum_k A[m][k]*W[co][k]; A (n,c) bf16 stride strideA; W [co][Ktot].
// NSLICES=9: implicit 3x3 conv, K-chunk t -> (cib=t/9, s=t%9), slice-inner order.
// EPI 0: store bf16; EPI 2: d_out NCHW f32 = res(n,c) + (1-alpha)*acc.
// K-loop: STAGE(t+1); vmcnt(8) [stage t landed, t+1 in flight]; s_barrier;
//         compute(t); s_barrier [readers done before buf reuse].
template<int EPI, int NSLICES>
__global__ __launch_bounds__(512, 2)
void gemm256_k(const unsigned short* __restrict__ A, int strideA,
               const unsigned short* __restrict__ W, int Ktot,
               int NcolsW, int NcolsStore, int outStride, int colBlocks,
               unsigned short* __restrict__ outB,
               const float* __restrict__ res, float* __restrict__ outF,
               const float* __restrict__ alphaP,
               const unsigned short* __restrict__ zerop)
{
  __shared__ unsigned short lds[65536];   // 128 KiB: A[2][256][64] then B[2][256][64]

  const int tid = threadIdx.x;
  const int l  = tid & 63;
  const int w  = tid >> 6;
  const int wm = w >> 2;        // 0..1  (M half)
  const int wn = w & 3;         // 0..3  (N quarter)

  // XCD-chunked bijective swizzle (grid % 8 == 0)
  const int q8 = gridDim.x >> 3;
  const int bid = (blockIdx.x & 7)*q8 + (blockIdx.x >> 3);
  const int mblk = bid / colBlocks;
  const int nblk = bid - mblk*colBlocks;
  const int m0 = mblk*256, co0 = nblk*256;

  // ---- staging geometry: instr i in 0..3, row = (w*4+i)*8 + (l>>3), slot = l&7
  int rowT[4], slotX[4];
  #pragma unroll
  for (int i = 0; i < 4; i++){
    rowT[i]  = (w*4 + i)*8 + (l >> 3);
    slotX[i] = (l & 7) ^ (rowT[i] & 7);
  }
  const unsigned short* baseA[4];
  int hhA[4], wwA[4];
  #pragma unroll
  for (int i = 0; i < 4; i++){
    int gm = m0 + rowT[i];
    int np = gm & (NPIX-1);
    hhA[i] = np >> 7; wwA[i] = np & 127;
    baseA[i] = A + (size_t)gm*strideA + (slotX[i] << 3);
  }
  const unsigned short* baseB[4];
  bool bval[4];
  #pragma unroll
  for (int i = 0; i < 4; i++){
    int co = co0 + rowT[i];
    bval[i] = (co < NcolsW);
    baseB[i] = bval[i] ? (W + (size_t)co*Ktot + (slotX[i] << 3)) : (zerop + (l << 3));
  }

  const int NT = Ktot >> 6;

  auto STAGE = [&](int ts){
    int buf = ts & 1;
    unsigned short* la = lds + buf*16384;
    unsigned short* lb = lds + 32768 + buf*16384;
    int ci0, dy = 0, dx = 0;
    if constexpr (NSLICES == 1){ ci0 = ts << 6; }
    else { int cib = ts/9, s = ts - cib*9; ci0 = cib << 6; dy = s/3 - 1; dx = s - (s/3)*3 - 1; }
    #pragma unroll
    for (int i = 0; i < 4; i++){
      const unsigned short* srcA;
      if constexpr (NSLICES == 1){
        srcA = baseA[i] + ci0;
      } else {
        int h2 = hhA[i] + dy, w2 = wwA[i] + dx;
        srcA = ((unsigned)h2 < 128u && (unsigned)w2 < 128u)
             ? (baseA[i] + (dy*HH + dx)*strideA + ci0)
             : (zerop + (l << 3));
      }
      gload16(srcA, la + (w*4 + i)*512);
    }
    #pragma unroll
    for (int i = 0; i < 4; i++){
      const unsigned short* srcB = bval[i] ? (baseB[i] + (ts << 6)) : baseB[i];
      gload16(srcB, lb + (w*4 + i)*512);
    }
  };

  f32x4 acc[8][4] = {};

  STAGE(0);
  for (int t = 0; t < NT; ++t){
    if (t + 1 < NT){
      STAGE(t + 1);
      asm volatile("s_waitcnt vmcnt(8)" ::: "memory");   // stage t landed; t+1 in flight
    } else {
      asm volatile("s_waitcnt vmcnt(0)" ::: "memory");
    }
    __builtin_amdgcn_s_barrier();
    asm volatile("" ::: "memory");
    const unsigned short* la = lds + (t & 1)*16384;
    const unsigned short* lb = lds + 32768 + (t & 1)*16384;
    __builtin_amdgcn_s_setprio(1);
    #pragma unroll
    for (int kk = 0; kk < 2; kk++){
      int ks = kk*4 + (l >> 4);
      bf16x8 bf[4];
      #pragma unroll
      for (int nf = 0; nf < 4; nf++){
        int rb = wn*64 + nf*16 + (l & 15);
        bf[nf] = *(const bf16x8*)(lb + rb*64 + ((ks ^ (rb & 7)) << 3));
      }
      #pragma unroll
      for (int mf = 0; mf < 8; mf++){
        int rm = wm*128 + mf*16 + (l & 15);
        bf16x8 af = *(const bf16x8*)(la + rm*64 + ((ks ^ (rm & 7)) << 3));
        #pragma unroll
        for (int nf = 0; nf < 4; nf++)
          acc[mf][nf] = __builtin_amdgcn_mfma_f32_16x16x32_bf16(af, bf[nf], acc[mf][nf], 0, 0, 0);
      }
    }
    __builtin_amdgcn_s_setprio(0);
    asm volatile("" ::: "memory");
    __builtin_amdgcn_s_barrier();   // all readers done before next STAGE overwrites
  }

  float alpha = (EPI == 2) ? (1.f - *alphaP) : 0.f;
  #pragma unroll
  for (int mf = 0; mf < 8; mf++){
    int r0 = m0 + wm*128 + mf*16 + ((l >> 4) << 2);
    #pragma unroll
    for (int nf = 0; nf < 4; nf++){
      int co = co0 + wn*64 + nf*16 + (l & 15);
      if (co < NcolsStore){
        #pragma unroll
        for (int r = 0; r < 4; r++){
          int gm = r0 + r;
          float v = acc[mf][nf][r];
          if constexpr (EPI == 0){
            outB[(size_t)gm*outStride + co] = f2b(v);
          } else {
            int b = gm >> 14, np = gm & (NPIX-1);
            outF[((size_t)b*CC + co)*NPIX + np] = res[(size_t)gm*CC + co] + alpha*v;
          }
        }
      }
    }
  }
}

// ---------------- MFMA GEMM 128x128, dbuf + counted vmcnt (K=192 GEMMs) ----------------
template<int EPI>
__global__ __launch_bounds__(256, 2)
void gemm_k(const unsigned short* __restrict__ A, int strideA,
            const unsigned short* __restrict__ W, int Ktot,
            int NcolsW, int NcolsStore, int outStride, int colBlocks,
            unsigned short* __restrict__ outB,
            const float* __restrict__ bias,
            const float* __restrict__ res,
            float* __restrict__ outF,
            const float* __restrict__ alphaP,
            const unsigned short* __restrict__ zerop)
{
  __shared__ unsigned short lds[32768];   // 64 KiB: [2][ A[128][64] | B[128][64] ]

  const int tid = threadIdx.x;
  const int lane = tid & 63;
  const int wv = tid >> 6;
  const int q8 = gridDim.x >> 3;
  const int bid = (blockIdx.x & 7)*q8 + (blockIdx.x >> 3);
  const int mblk = bid / colBlocks;
  const int nblk = bid - mblk*colBlocks;
  const int m0 = mblk*128, co0 = nblk*128;

  int rowT[4], slotX[4];
  const unsigned short *baseA[4], *baseB[4];
  bool bval[4];
  #pragma unroll
  for (int i = 0; i < 4; i++){
    rowT[i]  = wv*32 + i*8 + (lane >> 3);
    slotX[i] = (lane & 7) ^ (rowT[i] & 7);
    baseA[i] = A + (size_t)(m0 + rowT[i])*strideA + (slotX[i] << 3);
    int co = co0 + rowT[i];
    bval[i] = (co < NcolsW);
    baseB[i] = bval[i] ? (W + (size_t)co*Ktot + (slotX[i] << 3)) : (zerop + (lane << 3));
  }

  const int NT = Ktot >> 6;

  auto STAGE = [&](int ts){
    unsigned short* la = lds + (ts & 1)*16384;
    #pragma unroll
    for (int i = 0; i < 4; i++)
      gload16(baseA[i] + (ts << 6), (char*)la + (wv*4 + i)*1024);
    #pragma unroll
    for (int i = 0; i < 4; i++)
      gload16(bval[i] ? (baseB[i] + (ts << 6)) : baseB[i],
              (char*)la + 16384 + (wv*4 + i)*1024);
  };

  f32x4 acc[4][4] = {};

  STAGE(0);
  for (int t = 0; t < NT; ++t){
    if (t + 1 < NT){
      STAGE(t + 1);
      asm volatile("s_waitcnt vmcnt(8)" ::: "memory");
    } else {
      asm volatile("s_waitcnt vmcnt(0)" ::: "memory");
    }
    __builtin_amdgcn_s_barrier();
    asm volatile("" ::: "memory");
    const unsigned short* la = lds + (t & 1)*16384;
    const unsigned short* lb = la + 8192;
    __builtin_amdgcn_s_setprio(1);
    #pragma unroll
    for (int kk = 0; kk < 2; kk++){
      int ks = kk*4 + (lane >> 4);
      bf16x8 af[4], bfr[4];
      #pragma unroll
      for (int mi = 0; mi < 4; mi++){
        int rm = (wv >> 1)*64 + mi*16 + (lane & 15);
        af[mi] = *(const bf16x8*)(la + rm*64 + ((ks ^ (rm & 7)) << 3));
      }
      #pragma unroll
      for (int ni = 0; ni < 4; ni++){
        int rb = (wv & 1)*64 + ni*16 + (lane & 15);
        bfr[ni] = *(const bf16x8*)(lb + rb*64 + ((ks ^ (rb & 7)) << 3));
      }
      #pragma unroll
      for (int mi = 0; mi < 4; mi++)
        #pragma unroll
        for (int ni = 0; ni < 4; ni++)
          acc[mi][ni] = __builtin_amdgcn_mfma_f32_16x16x32_bf16(af[mi], bfr[ni], acc[mi][ni], 0, 0, 0);
    }
    __builtin_amdgcn_s_setprio(0);
    asm volatile("" ::: "memory");
    __builtin_amdgcn_s_barrier();
  }

  float alpha = 0.f;
  if (EPI == 1) alpha = *alphaP;
  const int colb = co0 + (wv & 1)*64;
  const int rowb = m0 + (wv >> 1)*64;
  #pragma unroll
  for (int mi = 0; mi < 4; mi++){
    int r0 = rowb + mi*16 + ((lane >> 4) << 2);
    #pragma unroll
    for (int ni = 0; ni < 4; ni++){
      int co = colb + ni*16 + (lane & 15);
      if (co < NcolsStore){
        float bv = (EPI == 0 && bias) ? bias[co] : 0.f;
        #pragma unroll
        for (int r = 0; r < 4; r++){
          int gm = r0 + r;
          float v = acc[mi][ni][r];
          if constexpr (EPI == 0){
            outB[(size_t)gm*outStride + co] = f2b(v + bv);
          } else {
            int b = gm >> 14, np = gm & (NPIX-1);
            outF[(size_t)gm*CC + co] = res[((size_t)b*CC + co)*NPIX + np] + alpha*v;
          }
        }
      }
    }
  }
}

// ---------------- Depthwise 3x3 (+optional SiLU), (n,c) bf16, [s][c] weights ----------------
template<int NCHV, int DOSILU>
__global__ __launch_bounds__(256)
void dw_k(const unsigned short* __restrict__ src, int strideS,
          const float* __restrict__ wtT, int wstride,
          unsigned short* __restrict__ dst, int strideD)
{
  const int q8 = gridDim.x >> 3;
  const int bid = (blockIdx.x & 7)*q8 + (blockIdx.x >> 3);
  int idx = bid*256 + threadIdx.x;
  int gm = idx / NCHV;
  int cb = idx - gm*NCHV;
  int c = cb*8;
  int np = gm & (NPIX-1);
  int hh = np >> 7, ww = np & 127;
  float acc[8] = {0,0,0,0,0,0,0,0};
  #pragma unroll
  for (int s = 0; s < 9; s++){
    int dy = s/3 - 1, dx = s%3 - 1;
    int h2 = hh + dy, w2 = ww + dx;
    if ((unsigned)h2 < 128u && (unsigned)w2 < 128u){
      us8 t = *(const us8*)(src + (size_t)(gm + dy*HH + dx)*strideS + c);
      f32x4 w0 = *(const f32x4*)(wtT + s*wstride + c);
      f32x4 w1 = *(const f32x4*)(wtT + s*wstride + c + 4);
      #pragma unroll
      for (int j = 0; j < 4; j++){
        acc[j]   += b2f(t[j])   * w0[j];
        acc[4+j] += b2f(t[4+j]) * w1[j];
      }
    }
  }
  us8 o;
  #pragma unroll
  for (int j = 0; j < 8; j++){
    float v = acc[j];
    if (DOSILU) v = v / (1.f + __expf(-v));
    o[j] = f2b(v);
  }
  *(us8*)(dst + (size_t)gm*strideD + c) = o;
}

// ---------------- per-(b,c) sum of squares over n (partials) ----------------
__global__ __launch_bounds__(192)
void sumsq_k(const unsigned short* __restrict__ q, int stride, float* __restrict__ part)
{
  int b = blockIdx.x >> 5, ch = blockIdx.x & 31;
  int c = threadIdx.x;
  const unsigned short* base = q + ((size_t)b*NPIX + ch*512)*stride + c;
  float acc = 0.f;
  for (int r = 0; r < 512; r++){ float v = b2f(base[(size_t)r*stride]); acc += v*v; }
  part[(size_t)(b*32 + ch)*CC + c] = acc;
}

// ---------------- QK^T partials: S[c][d] = sum_n q[c,n]k[d,n] ----------------
// Register-tiled: lane owns 4c x 4d; [n][c] bf16 LDS tiles, contiguous staging.
__global__ __launch_bounds__(256)
void pairdot_k(const unsigned short* __restrict__ qb, const unsigned short* __restrict__ kb,
               int stride, float* __restrict__ Spart)
{
  __shared__ unsigned short qt[4096];   // [128][32] bf16, [n][c]
  __shared__ unsigned short kt[4096];
  __shared__ float part[4][32][32];
  int bh = blockIdx.x >> 3, chunk = blockIdx.x & 7;
  int b = bh / HEADS, h = bh - b*HEADS;
  int t = threadIdx.x;
  int w = t >> 6, l = t & 63;
  int c4 = l >> 3, d4 = l & 7;
  size_t gm0 = (size_t)b*NPIX + (size_t)chunk*2048;
  int srow = t >> 2, scol = (t & 3) << 3;
  float acc[4][4] = {};
  for (int sub = 0; sub < 16; sub++){
    __syncthreads();
    #pragma unroll
    for (int hh2 = 0; hh2 < 2; hh2++){
      size_t gr = gm0 + sub*128 + hh2*64 + srow;
      us8 vq = *(const us8*)(qb + gr*stride + h*32 + scol);
      us8 vk = *(const us8*)(kb + gr*stride + h*32 + scol);
      *(us8*)(qt + hh2*2048 + t*8) = vq;    // byte t*16: contiguous, conflict-free
      *(us8*)(kt + hh2*2048 + t*8) = vk;
    }
    __syncthreads();
    #pragma unroll 4
    for (int nn = 0; nn < 32; nn++){
      int n = w*32 + nn;
      us4 qv = *(const us4*)(qt + n*32 + c4*4);
      us4 kv = *(const us4*)(kt + n*32 + d4*4);
      float qf[4], kf[4];
      #pragma unroll
      for (int i = 0; i < 4; i++){ qf[i] = b2f(qv[i]); kf[i] = b2f(kv[i]); }
      #pragma unroll
      for (int i = 0; i < 4; i++)
        #pragma unroll
        for (int j = 0; j < 4; j++)
          acc[i][j] += qf[i]*kf[j];
    }
  }
  __syncthreads();
  #pragma unroll
  for (int i = 0; i < 4; i++)
    #pragma unroll
    for (int j = 0; j < 4; j++)
      part[w][c4*4 + i][d4*4 + j] = acc[i][j];
  __syncthreads();
  #pragma unroll
  for (int o = t; o < 1024; o += 256){
    int c = o >> 5, d = o & 31;
    Spart[(size_t)blockIdx.x*1024 + o] =
      part[0][c][d] + part[1][c][d] + part[2][c][d] + part[3][c][d];
  }
}

// ---------------- softmax(cfa)+softmax(pos) combine ----------------
__global__ __launch_bounds__(64)
void smax_k(const float* __restrict__ Spos, const float* __restrict__ Scfa,
            const float* __restrict__ qnp, const float* __restrict__ knp,
            const float* __restrict__ temp, float* __restrict__ att)
{
  int bh = blockIdx.x; int b = bh / HEADS, h = bh - b*HEADS;
  __shared__ float kn[32];
  int t = threadIdx.x;
  if (t < 32){
    float ss = 0.f;
    for (int ck = 0; ck < 32; ck++) ss += knp[((size_t)b*32 + ck)*CC + h*32 + t];
    kn[t] = fmaxf(sqrtf(ss), 1e-12f);
  }
  __syncthreads();
  if (t >= 32) return;
  int c = t;
  float ssq = 0.f;
  for (int ck = 0; ck < 32; ck++) ssq += qnp[((size_t)b*32 + ck)*CC + h*32 + c];
  float qn = fmaxf(sqrtf(ssq), 1e-12f);
  float rowS[32], rowP[32];
  #pragma unroll
  for (int d = 0; d < 32; d++){
    float sv = 0.f, pv = 0.f;
    for (int ck = 0; ck < 8; ck++){
      sv += Scfa[(size_t)(bh*8 + ck)*1024 + c*32 + d];
      pv += Spos[(size_t)(bh*8 + ck)*1024 + c*32 + d];
    }
    rowS[d] = sv; rowP[d] = pv;
  }
  float tv = temp[h];
  float m1 = -3e38f, m2 = -3e38f;
  #pragma unroll
  for (int d = 0; d < 32; d++){
    rowS[d] = rowS[d] / (qn*kn[d]) * tv;
    m1 = fmaxf(m1, rowS[d]);
    m2 = fmaxf(m2, rowP[d]);
  }
  float s1 = 0.f, s2 = 0.f;
  #pragma unroll
  for (int d = 0; d < 32; d++){
    rowS[d] = __expf(rowS[d] - m1); s1 += rowS[d];
    rowP[d] = __expf(rowP[d] - m2); s2 += rowP[d];
  }
  float r1 = 1.f/s1, r2 = 1.f/s2;
  #pragma unroll
  for (int d = 0; d < 32; d++)
    att[(size_t)bh*1024 + c*32 + d] = rowS[d]*r1 + rowP[d]*r2;
}

// ---------------- PV: outT[n][c] = sum_d att[c][d] * v[d][n] ----------------
__global__ __launch_bounds__(256)
void pv_k(const float* __restrict__ att, const unsigned short* __restrict__ vd, int stride,
          unsigned short* __restrict__ outT)
{
  __shared__ float As[32][33];
  int bh = blockIdx.x >> 8; int mc = blockIdx.x & 255;
  int b = bh / HEADS, h = bh - b*HEADS;
  int t = threadIdx.x;
  for (int i = t; i < 1024; i += 256) As[i >> 5][i & 31] = att[(size_t)bh*1024 + i];
  __syncthreads();
  int gm = b*NPIX + mc*64 + (t >> 2);
  int cq = t & 3;
  const unsigned short* vp = vd + (size_t)gm*stride + h*32;
  float acc[8] = {0,0,0,0,0,0,0,0};
  for (int d = 0; d < 32; d++){
    float vv = b2f(vp[d]);
    #pragma unroll
    for (int j = 0; j < 8; j++) acc[j] += As[cq*8 + j][d] * vv;
  }
  us8 o;
  #pragma unroll
  for (int j = 0; j < 8; j++) o[j] = f2b(acc[j]);
  *(us8*)(outT + (size_t)gm*CC + h*32 + cq*8) = o;
}

// ---------------- weight prep ----------------
__global__ void castcopy_k(const float* __restrict__ s, unsigned short* __restrict__ d, int n){
  int i = blockIdx.x*256 + threadIdx.x; if (i < n) d[i] = f2b(s[i]);
}
// SEL-in W: [co][cib][s][ci64], cib=0..2 (C=192), chunk = cib*9+s
__global__ void prepselin_k(const float* __restrict__ s, unsigned short* __restrict__ d){
  int i = blockIdx.x*256 + threadIdx.x;
  if (i >= 510*1728) return;
  int co = i / 1728, rem = i - co*1728;
  int chunk = rem >> 6, e = rem & 63;
  int cib = chunk / 9, sl = chunk - cib*9;
  int ci = cib*64 + e;
  d[i] = f2b(s[(size_t)(co*192 + ci)*9 + sl]);
}
// SEL-out W: [co][cib][s][ci64], cib=0..7 (C=512 padded), chunk = cib*9+s
__global__ void prepselout_k(const float* __restrict__ s, unsigned short* __restrict__ d){
  int i = blockIdx.x*256 + threadIdx.x;
  if (i >= 192*4608) return;
  int co = i / 4608, rem = i - co*4608;
  int chunk = rem >> 6, e = rem & 63;
  int cib = chunk / 9, sl = chunk - cib*9;
  int ci = cib*64 + e;
  d[i] = (ci < 510) ? f2b(s[(size_t)(co*510 + ci)*9 + sl]) : (unsigned short)0;
}
// bias for combined 960-col GEMM: cols 0..383 = pos_embed projections, rest 0
__global__ void prepbias_k(const float* __restrict__ pq, const float* __restrict__ pk,
                           const float* __restrict__ pe, float* __restrict__ bias){
  int r = blockIdx.x*64 + threadIdx.x;
  if (r >= 960) return;
  float s = 0.f;
  if (r < 384){
    const float* Wp = (r < 192) ? pq : pk;
    int co = (r < 192) ? r : r - 192;
    for (int ci = 0; ci < 192; ci++) s += Wp[co*192 + ci]*pe[ci];
  }
  bias[r] = s;
}
// dw weights -> [s][c] transposed layouts (qkv fused 576; sel padded 512)
__global__ void prepdwT_k(const float* __restrict__ qdw, const float* __restrict__ kvdw,
                          const float* __restrict__ seldw,
                          float* __restrict__ wqkv, float* __restrict__ wsel){
  int i = blockIdx.x*256 + threadIdx.x;
  if (i < 9*576){
    int s = i / 576, c = i - s*576;
    wqkv[i] = (c < 192) ? qdw[c*9 + s] : kvdw[(size_t)(c-192)*9 + s];
  }
  int j = i - 9*576;
  if (j >= 0 && j < 9*512){
    int s = j / 512, c = j - s*512;
    wsel[j] = (c < 510) ? seldw[(size_t)c*9 + s] : 0.f;
  }
}

// ---------------- launch ----------------
extern "C" void kernel_launch(void* const* d_in, const int* in_sizes, int n_in,
                              void* d_out, int out_size, void* d_ws, size_t ws_size,
                              hipStream_t stream)
{
  const float* x       = (const float*)d_in[0];
  const float* ln_w    = (const float*)d_in[1];
  const float* ln_b    = (const float*)d_in[2];
  const float* temp    = (const float*)d_in[3];
  const float* q_w     = (const float*)d_in[4];
  const float* q_dw    = (const float*)d_in[5];
  const float* kv_w    = (const float*)d_in[6];
  const float* kv_dw   = (const float*)d_in[7];
  const float* proj_w  = (const float*)d_in[8];
  const float* pos_e   = (const float*)d_in[9];
  const float* posq_w  = (const float*)d_in[10];
  const float* posk_w  = (const float*)d_in[11];
  const float* selin_w = (const float*)d_in[12];
  const float* seldw_w = (const float*)d_in[13];
  const float* selout_w= (const float*)d_in[14];
  const float* alphaP  = (const float*)d_in[15];

  char* ws = (char*)d_ws;
  unsigned short* zerop  = (unsigned short*)(ws + 0);         // 4KB zeros
  float* biasC           = (float*)(ws + 4096);               // 960 f32
  float* Spos            = (float*)(ws + 8192);               // 24*8*1024 f32
  float* Scfa            = (float*)(ws + 794624);
  float* qnp             = (float*)(ws + 1581056);            // 4*32*192 f32
  float* knp             = (float*)(ws + 1679360);
  float* att             = (float*)(ws + 1777664);            // 24*1024 f32
  unsigned short* WC     = (unsigned short*)(ws + 2097152);   // 960x192 bf16 (posq,posk,q,kv)
  unsigned short* Wproj  = (unsigned short*)(ws + 2465792);   // 192x192
  unsigned short* Wselin = (unsigned short*)(ws + 2539520);   // 510x1728
  unsigned short* Wselout= (unsigned short*)(ws + 4302080);   // 192x4608
  float* WdwQKV          = (float*)(ws + 6071552);            // 9x576 f32
  float* WdwSEL          = (float*)(ws + 6092288);            // 9x512 f32
  // big regions (sequenced reuse)
  unsigned short* normx  = (unsigned short*)(ws + 8388608);   // A: normx -> outT (25.2MB)
  unsigned short* outT   = normx;
  unsigned short* qp     = (unsigned short*)(ws + 33554432);  // B: qp(126MB) -> x2(50.3) + nx/g2
  float*          x2     = (float*)(ws + 33554432);
  unsigned short* nx     = (unsigned short*)(ws + 83886080);
  unsigned short* g2     = (unsigned short*)(ws + 83886080);
  unsigned short* qkvd   = (unsigned short*)(ws + 159383552); // C: qkvd(75.5MB) -> g(67MB)
  unsigned short* g      = qkvd;

  hipMemsetAsync(zerop, 0, 4096, stream);

  // weight prep
  castcopy_k<<<144, 256, 0, stream>>>(posq_w, WC,          36864);
  castcopy_k<<<144, 256, 0, stream>>>(posk_w, WC + 36864,  36864);
  castcopy_k<<<144, 256, 0, stream>>>(q_w,    WC + 73728,  36864);
  castcopy_k<<<288, 256, 0, stream>>>(kv_w,   WC + 110592, 73728);
  castcopy_k<<<144, 256, 0, stream>>>(proj_w, Wproj,       36864);
  prepselin_k<<<3443, 256, 0, stream>>>(selin_w, Wselin);
  prepselout_k<<<3456, 256, 0, stream>>>(selout_w, Wselout);
  prepbias_k<<<15, 64, 0, stream>>>(posq_w, posk_w, pos_e, biasC);
  prepdwT_k<<<39, 256, 0, stream>>>(q_dw, kv_dw, seldw_w, WdwQKV, WdwSEL);

  // LN1
  ln1_k<<<1024, 256, 0, stream>>>(x, ln_w, ln_b, normx);
  // combined pos_q/pos_k/q/kv GEMM (960 cols, bias on first 384)
  gemm_k<0><<<512*8, 256, 0, stream>>>(normx, 192, WC, 192, 960, 960, 960, 8,
                                       qp, biasC, nullptr, nullptr, alphaP, zerop);
  // pos logits
  pairdot_k<<<192, 256, 0, stream>>>(qp, qp + 192, 960, Spos);
  // fused depthwise q,k,v -> qkvd (n,576)
  dw_k<72,0><<<18432, 256, 0, stream>>>(qp + 384, 960, WdwQKV, 576, qkvd, 576);
  // l2 norms (partials)
  sumsq_k<<<128, 192, 0, stream>>>(qkvd,       576, qnp);
  sumsq_k<<<128, 192, 0, stream>>>(qkvd + 192, 576, knp);
  // cfa logits
  pairdot_k<<<192, 256, 0, stream>>>(qkvd, qkvd + 192, 576, Scfa);
  // softmaxes + combine
  smax_k<<<24, 64, 0, stream>>>(Spos, Scfa, qnp, knp, temp, att);
  // PV
  pv_k<<<24*256, 256, 0, stream>>>(att, qkvd + 384, 576, outT);
  // proj + residual -> x2 (f32, (n,c))
  gemm_k<1><<<512*2, 256, 0, stream>>>(outT, 192, Wproj, 192, 192, 192, 192, 2,
                                       nullptr, nullptr, x, x2, alphaP, zerop);
  // LN2
  ln2_k<<<16384, 256, 0, stream>>>(x2, ln_w, ln_b, nx);
  // SEL in conv3x3 (implicit GEMM, K=1728) — 256^2 counted-vmcnt
  gemm256_k<0,9><<<512, 512, 0, stream>>>(nx, 192, Wselin, 1728, 510, 512, 512, 2,
                                          g, nullptr, nullptr, alphaP, zerop);
  // SEL depthwise + SiLU
  dw_k<64,1><<<16384, 256, 0, stream>>>(g, 512, WdwSEL, 512, g2, 512);
  // SEL out conv3x3 (K=4608) + final residual -> d_out NCHW — 256^2 counted-vmcnt
  gemm256_k<2,9><<<256, 512, 0, stream>>>(g2, 512, Wselout, 4608, 192, 192, 0, 1,
                                          nullptr, x2, (float*)d_out, alphaP, zerop);
}

// Round 9
// 805.758 us; speedup vs baseline: 2.3893x; 1.0612x over previous
//
#include <hip/hip_runtime.h>
#include <hip/hip_bf16.h>
#include <stdint.h>

#define DEVI __device__ __forceinline__

typedef __attribute__((ext_vector_type(8))) unsigned short us8;
typedef __attribute__((ext_vector_type(4))) unsigned short us4;
typedef __attribute__((ext_vector_type(8))) __bf16 bf16x8;
typedef __attribute__((ext_vector_type(4))) float f32x4;

#define BB 4
#define CC 192
#define HH 128
#define NPIX 16384
#define MTOT 65536
#define HEADS 6

DEVI float b2f(unsigned short u){ return __uint_as_float(((unsigned)u)<<16); }
DEVI unsigned short f2b(float f){
  unsigned u = __float_as_uint(f);
  return (unsigned short)((u + 0x7fffu + ((u>>16)&1u)) >> 16);
}

DEVI void gload16(const void* g, void* l){
  __builtin_amdgcn_global_load_lds((const __attribute__((address_space(1))) unsigned int*)g,
                                   (__attribute__((address_space(3))) unsigned int*)l,
                                   16, 0, 0);
}

// ---------------- LayerNorm 1: x NCHW f32 -> norm_x (n,c) bf16 ----------------
__global__ __launch_bounds__(256)
void ln1_k(const float* __restrict__ x, const float* __restrict__ lnw,
           const float* __restrict__ lnb, unsigned short* __restrict__ nx)
{
  __shared__ float tile[CC*65];
  __shared__ float stats[64*2];
  int gbase = blockIdx.x * 64;
  int b = gbase >> 14; int n0 = gbase & (NPIX-1);
  for (int idx = threadIdx.x; idx < CC*64; idx += 256){
    int c = idx >> 6, j = idx & 63;
    tile[c*65 + j] = x[((size_t)b*CC + c)*NPIX + n0 + j];
  }
  __syncthreads();
  if (threadIdx.x < 64){
    int j = threadIdx.x;
    float s = 0.f, ss = 0.f;
    for (int c = 0; c < CC; c++){ float v = tile[c*65 + j]; s += v; ss += v*v; }
    float mu = s * (1.f/CC);
    float var = ss * (1.f/CC) - mu*mu;
    stats[j*2] = mu; stats[j*2+1] = rsqrtf(var + 1e-6f);
  }
  __syncthreads();
  for (int idx = threadIdx.x; idx < CC*64; idx += 256){
    int c = idx % CC, j = idx / CC;
    float v = (tile[c*65 + j] - stats[j*2]) * stats[j*2+1] * lnw[c] + lnb[c];
    nx[(size_t)(gbase + j)*CC + c] = f2b(v);
  }
}

// ---------------- LayerNorm 2: x2 (n,c) f32 -> nx (n,c) bf16 ----------------
__global__ __launch_bounds__(256)
void ln2_k(const float* __restrict__ x2, const float* __restrict__ lnw,
           const float* __restrict__ lnb, unsigned short* __restrict__ nx)
{
  int gm = blockIdx.x*4 + (threadIdx.x >> 6);
  int lane = threadIdx.x & 63;
  const float* row = x2 + (size_t)gm*CC;
  float v0 = row[lane], v1 = row[lane+64], v2 = row[lane+128];
  float s = v0+v1+v2, ss = v0*v0+v1*v1+v2*v2;
  #pragma unroll
  for (int o = 32; o >= 1; o >>= 1){
    s  += __shfl_xor(s,  o);
    ss += __shfl_xor(ss, o);
  }
  float mu = s * (1.f/CC);
  float rstd = rsqrtf(ss*(1.f/CC) - mu*mu + 1e-6f);
  unsigned short* o0 = nx + (size_t)gm*CC;
  o0[lane]     = f2b((v0-mu)*rstd*lnw[lane]     + lnb[lane]);
  o0[lane+64]  = f2b((v1-mu)*rstd*lnw[lane+64]  + lnb[lane+64]);
  o0[lane+128] = f2b((v2-mu)*rstd*lnw[lane+128] + lnb[lane+128]);
}

// ======== 256xBN 8-wave dbuf GEMM, 4-phase interleaved K-step ========
// Wave grid WM x WN (8 waves); per-wave MF*16 rows x NF*16 cols. BM=256, BN=WN*NF*16.
// Phase p = (kk, mhalf): issue 2 stage loads of tile t+1, ds_read subset, MFMA cluster, barrier.
// vmcnt(0) at top of iteration = tile t landed (had a full K-step in flight).
template<int EPI, int NSLICES, int WM, int WN, int MF, int NF, int NB>
__global__ __launch_bounds__(512, 2)
void gemm256_k(const unsigned short* __restrict__ A, int strideA,
               const unsigned short* __restrict__ W, int Ktot,
               int NcolsW, int NcolsStore, int outStride, int colBlocks,
               unsigned short* __restrict__ outB,
               const float* __restrict__ res, float* __restrict__ outF,
               const float* __restrict__ alphaP,
               const unsigned short* __restrict__ zerop)
{
  constexpr int BN = WN*NF*16;
  __shared__ unsigned short lds[2*256*64 + 2*BN*64];   // A dbuf | B dbuf

  const int tid = threadIdx.x;
  const int l  = tid & 63;
  const int w  = tid >> 6;
  const int wm = w / WN;
  const int wn = w % WN;

  const int q8 = gridDim.x >> 3;
  const int bid = (blockIdx.x & 7)*q8 + (blockIdx.x >> 3);
  const int mblk = bid / colBlocks;
  const int nblk = bid - mblk*colBlocks;
  const int m0 = mblk*256, co0 = nblk*BN;

  // A staging rows (4 loads/thread)
  int rowA[4], slotA[4], hhA[4], wwA[4];
  const unsigned short* baseA[4];
  #pragma unroll
  for (int i = 0; i < 4; i++){
    rowA[i]  = (w*4 + i)*8 + (l >> 3);
    slotA[i] = (l & 7) ^ (rowA[i] & 7);
    int gm = m0 + rowA[i];
    int np = gm & (NPIX-1);
    hhA[i] = np >> 7; wwA[i] = np & 127;
    baseA[i] = A + (size_t)gm*strideA + (slotA[i] << 3);
  }
  // B staging rows (NB loads/thread)
  const unsigned short* baseB[NB];
  bool bval[NB];
  #pragma unroll
  for (int i = 0; i < NB; i++){
    int rowB = (w*NB + i)*8 + (l >> 3);
    int slot = (l & 7) ^ (rowB & 7);
    int co = co0 + rowB;
    bval[i] = (co < NcolsW);
    baseB[i] = bval[i] ? (W + (size_t)co*Ktot + (slot << 3)) : (zerop + (l << 3));
  }

  const int NT = Ktot >> 6;

  auto STAGE_PART = [&](int ts, int p){
    unsigned short* la = lds + (ts & 1)*16384;
    unsigned short* lb = lds + 32768 + (ts & 1)*(BN*64);
    int ci0, dy = 0, dx = 0;
    if constexpr (NSLICES == 9){
      int cib = ts/9, s = ts - cib*9; ci0 = cib << 6; dy = s/3 - 1; dx = s - (s/3)*3 - 1;
    } else { ci0 = ts << 6; }
    if (p < 2){
      #pragma unroll
      for (int ii = 0; ii < 2; ii++){
        int i = p*2 + ii;
        const unsigned short* srcA;
        if constexpr (NSLICES == 9){
          int h2 = hhA[i] + dy, w2 = wwA[i] + dx;
          srcA = ((unsigned)h2 < 128u && (unsigned)w2 < 128u)
               ? (baseA[i] + (dy*HH + dx)*strideA + ci0)
               : (zerop + (l << 3));
        } else {
          srcA = baseA[i] + ci0;
        }
        gload16(srcA, la + (w*4 + i)*512);
      }
    } else if (p == 2){
      #pragma unroll
      for (int i = 0; i < 2; i++)
        gload16(bval[i] ? (baseB[i] + (ts << 6)) : baseB[i], lb + (w*NB + i)*512);
    } else {
      #pragma unroll
      for (int i = 2; i < NB; i++)
        gload16(bval[i] ? (baseB[i] + (ts << 6)) : baseB[i], lb + (w*NB + i)*512);
    }
  };

  f32x4 acc[MF][NF] = {};

  #pragma unroll
  for (int p = 0; p < 4; p++) STAGE_PART(0, p);

  for (int t = 0; t < NT; ++t){
    asm volatile("s_waitcnt vmcnt(0)" ::: "memory");   // tile t landed
    __builtin_amdgcn_s_barrier();
    asm volatile("" ::: "memory");
    const unsigned short* la = lds + (t & 1)*16384;
    const unsigned short* lb = lds + 32768 + (t & 1)*(BN*64);
    bf16x8 bfr[NF];
    #pragma unroll
    for (int ph = 0; ph < 4; ph++){
      const int kk = ph >> 1, mh = ph & 1;
      if (t + 1 < NT) STAGE_PART(t + 1, ph);
      const int ks = kk*4 + (l >> 4);
      if (mh == 0){
        #pragma unroll
        for (int nf = 0; nf < NF; nf++){
          int rb = wn*(NF*16) + nf*16 + (l & 15);
          bfr[nf] = *(const bf16x8*)(lb + rb*64 + ((ks ^ (rb & 7)) << 3));
        }
      }
      __builtin_amdgcn_s_setprio(1);
      #pragma unroll
      for (int mi = 0; mi < MF/2; mi++){
        int mf = mh*(MF/2) + mi;
        int rm = wm*(MF*16) + mf*16 + (l & 15);
        bf16x8 af = *(const bf16x8*)(la + rm*64 + ((ks ^ (rm & 7)) << 3));
        #pragma unroll
        for (int nf = 0; nf < NF; nf++)
          acc[mf][nf] = __builtin_amdgcn_mfma_f32_16x16x32_bf16(af, bfr[nf], acc[mf][nf], 0, 0, 0);
      }
      __builtin_amdgcn_s_setprio(0);
      asm volatile("" ::: "memory");
      if (ph < 3){ __builtin_amdgcn_s_barrier(); asm volatile("" ::: "memory"); }
    }
  }

  float alpha = (EPI == 2) ? (1.f - *alphaP) : 0.f;
  #pragma unroll
  for (int mf = 0; mf < MF; mf++){
    int r0 = m0 + wm*(MF*16) + mf*16 + ((l >> 4) << 2);
    #pragma unroll
    for (int nf = 0; nf < NF; nf++){
      int co = co0 + wn*(NF*16) + nf*16 + (l & 15);
      if (co < NcolsStore){
        #pragma unroll
        for (int r = 0; r < 4; r++){
          int gm = r0 + r;
          float v = acc[mf][nf][r];
          if constexpr (EPI == 0){
            outB[(size_t)gm*outStride + co] = f2b(v);
          } else {
            int b = gm >> 14, np = gm & (NPIX-1);
            outF[((size_t)b*CC + co)*NPIX + np] = res[(size_t)gm*CC + co] + alpha*v;
          }
        }
      }
    }
  }
}

// ---------------- MFMA GEMM 128x128, dbuf + counted vmcnt (K=192 GEMMs) ----------------
// EPI 0 supports split output: cols < 384 -> outB (outStride), cols >= 384 -> outB2 (stride 576).
template<int EPI>
__global__ __launch_bounds__(256, 2)
void gemm_k(const unsigned short* __restrict__ A, int strideA,
            const unsigned short* __restrict__ W, int Ktot,
            int NcolsW, int NcolsStore, int outStride, int colBlocks,
            unsigned short* __restrict__ outB,
            unsigned short* __restrict__ outB2,
            const float* __restrict__ bias,
            const float* __restrict__ res,
            float* __restrict__ outF,
            const float* __restrict__ alphaP,
            const unsigned short* __restrict__ zerop)
{
  __shared__ unsigned short lds[32768];

  const int tid = threadIdx.x;
  const int lane = tid & 63;
  const int wv = tid >> 6;
  const int q8 = gridDim.x >> 3;
  const int bid = (blockIdx.x & 7)*q8 + (blockIdx.x >> 3);
  const int mblk = bid / colBlocks;
  const int nblk = bid - mblk*colBlocks;
  const int m0 = mblk*128, co0 = nblk*128;

  int rowT[4], slotX[4];
  const unsigned short *baseA[4], *baseB[4];
  bool bval[4];
  #pragma unroll
  for (int i = 0; i < 4; i++){
    rowT[i]  = wv*32 + i*8 + (lane >> 3);
    slotX[i] = (lane & 7) ^ (rowT[i] & 7);
    baseA[i] = A + (size_t)(m0 + rowT[i])*strideA + (slotX[i] << 3);
    int co = co0 + rowT[i];
    bval[i] = (co < NcolsW);
    baseB[i] = bval[i] ? (W + (size_t)co*Ktot + (slotX[i] << 3)) : (zerop + (lane << 3));
  }

  const int NT = Ktot >> 6;

  auto STAGE = [&](int ts){
    unsigned short* la = lds + (ts & 1)*16384;
    #pragma unroll
    for (int i = 0; i < 4; i++)
      gload16(baseA[i] + (ts << 6), (char*)la + (wv*4 + i)*1024);
    #pragma unroll
    for (int i = 0; i < 4; i++)
      gload16(bval[i] ? (baseB[i] + (ts << 6)) : baseB[i],
              (char*)la + 16384 + (wv*4 + i)*1024);
  };

  f32x4 acc[4][4] = {};

  STAGE(0);
  for (int t = 0; t < NT; ++t){
    if (t + 1 < NT){
      STAGE(t + 1);
      asm volatile("s_waitcnt vmcnt(8)" ::: "memory");
    } else {
      asm volatile("s_waitcnt vmcnt(0)" ::: "memory");
    }
    __builtin_amdgcn_s_barrier();
    asm volatile("" ::: "memory");
    const unsigned short* la = lds + (t & 1)*16384;
    const unsigned short* lb = la + 8192;
    __builtin_amdgcn_s_setprio(1);
    #pragma unroll
    for (int kk = 0; kk < 2; kk++){
      int ks = kk*4 + (lane >> 4);
      bf16x8 af[4], bfr[4];
      #pragma unroll
      for (int mi = 0; mi < 4; mi++){
        int rm = (wv >> 1)*64 + mi*16 + (lane & 15);
        af[mi] = *(const bf16x8*)(la + rm*64 + ((ks ^ (rm & 7)) << 3));
      }
      #pragma unroll
      for (int ni = 0; ni < 4; ni++){
        int rb = (wv & 1)*64 + ni*16 + (lane & 15);
        bfr[ni] = *(const bf16x8*)(lb + rb*64 + ((ks ^ (rb & 7)) << 3));
      }
      #pragma unroll
      for (int mi = 0; mi < 4; mi++)
        #pragma unroll
        for (int ni = 0; ni < 4; ni++)
          acc[mi][ni] = __builtin_amdgcn_mfma_f32_16x16x32_bf16(af[mi], bfr[ni], acc[mi][ni], 0, 0, 0);
    }
    __builtin_amdgcn_s_setprio(0);
    asm volatile("" ::: "memory");
    __builtin_amdgcn_s_barrier();
  }

  float alpha = 0.f;
  if (EPI == 1) alpha = *alphaP;
  unsigned short* dstB = outB;
  int dstStr = outStride, coAdj = 0;
  if (EPI == 0 && outB2 && co0 >= 384){ dstB = outB2; dstStr = 576; coAdj = 384; }
  const int colb = co0 + (wv & 1)*64;
  const int rowb = m0 + (wv >> 1)*64;
  #pragma unroll
  for (int mi = 0; mi < 4; mi++){
    int r0 = rowb + mi*16 + ((lane >> 4) << 2);
    #pragma unroll
    for (int ni = 0; ni < 4; ni++){
      int co = colb + ni*16 + (lane & 15);
      if (co < NcolsStore){
        float bv = (EPI == 0 && bias) ? bias[co] : 0.f;
        #pragma unroll
        for (int r = 0; r < 4; r++){
          int gm = r0 + r;
          float v = acc[mi][ni][r];
          if constexpr (EPI == 0){
            dstB[(size_t)gm*dstStr + (co - coAdj)] = f2b(v + bv);
          } else {
            int b = gm >> 14, np = gm & (NPIX-1);
            outF[(size_t)gm*CC + co] = res[((size_t)b*CC + co)*NPIX + np] + alpha*v;
          }
        }
      }
    }
  }
}

// ---------------- Depthwise 3x3 (+optional SiLU), (n,c) bf16, [s][c] weights ----------------
template<int NCHV, int DOSILU>
__global__ __launch_bounds__(256)
void dw_k(const unsigned short* __restrict__ src, int strideS,
          const float* __restrict__ wtT, int wstride,
          unsigned short* __restrict__ dst, int strideD)
{
  const int q8 = gridDim.x >> 3;
  const int bid = (blockIdx.x & 7)*q8 + (blockIdx.x >> 3);
  int idx = bid*256 + threadIdx.x;
  int gm = idx / NCHV;
  int cb = idx - gm*NCHV;
  int c = cb*8;
  int np = gm & (NPIX-1);
  int hh = np >> 7, ww = np & 127;
  float acc[8] = {0,0,0,0,0,0,0,0};
  #pragma unroll
  for (int s = 0; s < 9; s++){
    int dy = s/3 - 1, dx = s%3 - 1;
    int h2 = hh + dy, w2 = ww + dx;
    if ((unsigned)h2 < 128u && (unsigned)w2 < 128u){
      us8 t = *(const us8*)(src + (size_t)(gm + dy*HH + dx)*strideS + c);
      f32x4 w0 = *(const f32x4*)(wtT + s*wstride + c);
      f32x4 w1 = *(const f32x4*)(wtT + s*wstride + c + 4);
      #pragma unroll
      for (int j = 0; j < 4; j++){
        acc[j]   += b2f(t[j])   * w0[j];
        acc[4+j] += b2f(t[4+j]) * w1[j];
      }
    }
  }
  us8 o;
  #pragma unroll
  for (int j = 0; j < 8; j++){
    float v = acc[j];
    if (DOSILU) v = v / (1.f + __expf(-v));
    o[j] = f2b(v);
  }
  *(us8*)(dst + (size_t)gm*strideD + c) = o;
}

// ---------------- per-(b,c) sum of squares over n: q and k in one launch ----------------
__global__ __launch_bounds__(192)
void sumsq2_k(const unsigned short* __restrict__ qkvd, float* __restrict__ qnp,
              float* __restrict__ knp)
{
  int which = blockIdx.x >> 7;
  int b = (blockIdx.x >> 5) & 3, ch = blockIdx.x & 31;
  int c = threadIdx.x;
  const unsigned short* base = qkvd + which*192 + ((size_t)b*NPIX + ch*512)*576 + c;
  float acc = 0.f;
  for (int r = 0; r < 512; r++){ float v = b2f(base[(size_t)r*576]); acc += v*v; }
  (which ? knp : qnp)[(size_t)(b*32 + ch)*CC + c] = acc;
}

// ---------------- QK^T partials: S[c][d] = sum_n q[c,n]k[d,n] ----------------
__global__ __launch_bounds__(256)
void pairdot_k(const unsigned short* __restrict__ qb, const unsigned short* __restrict__ kb,
               int stride, float* __restrict__ Spart)
{
  __shared__ unsigned short qt[4096];   // [128][32] bf16, [n][c]
  __shared__ unsigned short kt[4096];
  __shared__ float part[4][32][32];
  int bh = blockIdx.x >> 3, chunk = blockIdx.x & 7;
  int b = bh / HEADS, h = bh - b*HEADS;
  int t = threadIdx.x;
  int w = t >> 6, l = t & 63;
  int c4 = l >> 3, d4 = l & 7;
  size_t gm0 = (size_t)b*NPIX + (size_t)chunk*2048;
  int srow = t >> 2, scol = (t & 3) << 3;
  float acc[4][4] = {};
  for (int sub = 0; sub < 16; sub++){
    __syncthreads();
    #pragma unroll
    for (int hh2 = 0; hh2 < 2; hh2++){
      size_t gr = gm0 + sub*128 + hh2*64 + srow;
      us8 vq = *(const us8*)(qb + gr*stride + h*32 + scol);
      us8 vk = *(const us8*)(kb + gr*stride + h*32 + scol);
      *(us8*)(qt + hh2*2048 + t*8) = vq;
      *(us8*)(kt + hh2*2048 + t*8) = vk;
    }
    __syncthreads();
    #pragma unroll 4
    for (int nn = 0; nn < 32; nn++){
      int n = w*32 + nn;
      us4 qv = *(const us4*)(qt + n*32 + c4*4);
      us4 kv = *(const us4*)(kt + n*32 + d4*4);
      float qf[4], kf[4];
      #pragma unroll
      for (int i = 0; i < 4; i++){ qf[i] = b2f(qv[i]); kf[i] = b2f(kv[i]); }
      #pragma unroll
      for (int i = 0; i < 4; i++)
        #pragma unroll
        for (int j = 0; j < 4; j++)
          acc[i][j] += qf[i]*kf[j];
    }
  }
  __syncthreads();
  #pragma unroll
  for (int i = 0; i < 4; i++)
    #pragma unroll
    for (int j = 0; j < 4; j++)
      part[w][c4*4 + i][d4*4 + j] = acc[i][j];
  __syncthreads();
  #pragma unroll
  for (int o = t; o < 1024; o += 256){
    int c = o >> 5, d = o & 31;
    Spart[(size_t)blockIdx.x*1024 + o] =
      part[0][c][d] + part[1][c][d] + part[2][c][d] + part[3][c][d];
  }
}

// ---------------- softmax(cfa)+softmax(pos) combine ----------------
__global__ __launch_bounds__(64)
void smax_k(const float* __restrict__ Spos, const float* __restrict__ Scfa,
            const float* __restrict__ qnp, const float* __restrict__ knp,
            const float* __restrict__ temp, float* __restrict__ att)
{
  int bh = blockIdx.x; int b = bh / HEADS, h = bh - b*HEADS;
  __shared__ float kn[32];
  int t = threadIdx.x;
  if (t < 32){
    float ss = 0.f;
    for (int ck = 0; ck < 32; ck++) ss += knp[((size_t)b*32 + ck)*CC + h*32 + t];
    kn[t] = fmaxf(sqrtf(ss), 1e-12f);
  }
  __syncthreads();
  if (t >= 32) return;
  int c = t;
  float ssq = 0.f;
  for (int ck = 0; ck < 32; ck++) ssq += qnp[((size_t)b*32 + ck)*CC + h*32 + c];
  float qn = fmaxf(sqrtf(ssq), 1e-12f);
  float rowS[32], rowP[32];
  #pragma unroll
  for (int d = 0; d < 32; d++){
    float sv = 0.f, pv = 0.f;
    for (int ck = 0; ck < 8; ck++){
      sv += Scfa[(size_t)(bh*8 + ck)*1024 + c*32 + d];
      pv += Spos[(size_t)(bh*8 + ck)*1024 + c*32 + d];
    }
    rowS[d] = sv; rowP[d] = pv;
  }
  float tv = temp[h];
  float m1 = -3e38f, m2 = -3e38f;
  #pragma unroll
  for (int d = 0; d < 32; d++){
    rowS[d] = rowS[d] / (qn*kn[d]) * tv;
    m1 = fmaxf(m1, rowS[d]);
    m2 = fmaxf(m2, rowP[d]);
  }
  float s1 = 0.f, s2 = 0.f;
  #pragma unroll
  for (int d = 0; d < 32; d++){
    rowS[d] = __expf(rowS[d] - m1); s1 += rowS[d];
    rowP[d] = __expf(rowP[d] - m2); s2 += rowP[d];
  }
  float r1 = 1.f/s1, r2 = 1.f/s2;
  #pragma unroll
  for (int d = 0; d < 32; d++)
    att[(size_t)bh*1024 + c*32 + d] = rowS[d]*r1 + rowP[d]*r2;
}

// ---------------- PV: outT[n][c] = sum_d att[c][d] * v[d][n] ----------------
// Transposed att in LDS -> float4 reads; vectorized v loads.
__global__ __launch_bounds__(256)
void pv_k(const float* __restrict__ att, const unsigned short* __restrict__ vd, int stride,
          unsigned short* __restrict__ outT)
{
  __shared__ float At[32][36];   // At[d][c]
  int bh = blockIdx.x >> 8; int mc = blockIdx.x & 255;
  int b = bh / HEADS, h = bh - b*HEADS;
  int t = threadIdx.x;
  for (int i = t; i < 1024; i += 256){
    int c = i >> 5, d = i & 31;
    At[d][c] = att[(size_t)bh*1024 + i];
  }
  __syncthreads();
  int gm = b*NPIX + mc*64 + (t >> 2);
  int cq = t & 3;
  const unsigned short* vp = vd + (size_t)gm*stride + h*32;
  float vf[32];
  #pragma unroll
  for (int q8i = 0; q8i < 4; q8i++){
    us8 vv = *(const us8*)(vp + q8i*8);
    #pragma unroll
    for (int j = 0; j < 8; j++) vf[q8i*8 + j] = b2f(vv[j]);
  }
  float acc[8] = {0,0,0,0,0,0,0,0};
  #pragma unroll 8
  for (int d = 0; d < 32; d++){
    f32x4 a0 = *(const f32x4*)&At[d][cq*8];
    f32x4 a1 = *(const f32x4*)&At[d][cq*8 + 4];
    #pragma unroll
    for (int j = 0; j < 4; j++){
      acc[j]   += a0[j]*vf[d];
      acc[4+j] += a1[j]*vf[d];
    }
  }
  us8 o;
  #pragma unroll
  for (int j = 0; j < 8; j++) o[j] = f2b(acc[j]);
  *(us8*)(outT + (size_t)gm*CC + h*32 + cq*8) = o;
}

// ---------------- weight prep ----------------
// merged cast/copy: posq,posk,q,kv -> WC (960x192); proj -> Wproj
__global__ void prepw_k(const float* __restrict__ pq, const float* __restrict__ pk,
                        const float* __restrict__ qw, const float* __restrict__ kvw,
                        const float* __restrict__ pjw,
                        unsigned short* __restrict__ WC, unsigned short* __restrict__ Wproj){
  int i = blockIdx.x*256 + threadIdx.x;
  if (i < 36864)       WC[i] = f2b(pq[i]);
  else if (i < 73728)  WC[i] = f2b(pk[i - 36864]);
  else if (i < 110592) WC[i] = f2b(qw[i - 73728]);
  else if (i < 184320) WC[i] = f2b(kvw[i - 110592]);
  else if (i < 221184) Wproj[i - 184320] = f2b(pjw[i - 184320]);
}
// SEL-in W: [co][cib][s][ci64]
__global__ void prepselin_k(const float* __restrict__ s, unsigned short* __restrict__ d){
  int i = blockIdx.x*256 + threadIdx.x;
  if (i >= 510*1728) return;
  int co = i / 1728, rem = i - co*1728;
  int chunk = rem >> 6, e = rem & 63;
  int cib = chunk / 9, sl = chunk - cib*9;
  int ci = cib*64 + e;
  d[i] = f2b(s[(size_t)(co*192 + ci)*9 + sl]);
}
// SEL-out W: [co][cib][s][ci64], C padded to 512
__global__ void prepselout_k(const float* __restrict__ s, unsigned short* __restrict__ d){
  int i = blockIdx.x*256 + threadIdx.x;
  if (i >= 192*4608) return;
  int co = i / 4608, rem = i - co*4608;
  int chunk = rem >> 6, e = rem & 63;
  int cib = chunk / 9, sl = chunk - cib*9;
  int ci = cib*64 + e;
  d[i] = (ci < 510) ? f2b(s[(size_t)(co*510 + ci)*9 + sl]) : (unsigned short)0;
}
__global__ void prepbias_k(const float* __restrict__ pq, const float* __restrict__ pk,
                           const float* __restrict__ pe, float* __restrict__ bias){
  int r = blockIdx.x*64 + threadIdx.x;
  if (r >= 960) return;
  float s = 0.f;
  if (r < 384){
    const float* Wp = (r < 192) ? pq : pk;
    int co = (r < 192) ? r : r - 192;
    for (int ci = 0; ci < 192; ci++) s += Wp[co*192 + ci]*pe[ci];
  }
  bias[r] = s;
}
__global__ void prepdwT_k(const float* __restrict__ qdw, const float* __restrict__ kvdw,
                          const float* __restrict__ seldw,
                          float* __restrict__ wqkv, float* __restrict__ wsel){
  int i = blockIdx.x*256 + threadIdx.x;
  if (i < 9*576){
    int s = i / 576, c = i - s*576;
    wqkv[i] = (c < 192) ? qdw[c*9 + s] : kvdw[(size_t)(c-192)*9 + s];
  }
  int j = i - 9*576;
  if (j >= 0 && j < 9*512){
    int s = j / 512, c = j - s*512;
    wsel[j] = (c < 510) ? seldw[(size_t)c*9 + s] : 0.f;
  }
}

// ---------------- launch ----------------
extern "C" void kernel_launch(void* const* d_in, const int* in_sizes, int n_in,
                              void* d_out, int out_size, void* d_ws, size_t ws_size,
                              hipStream_t stream)
{
  const float* x       = (const float*)d_in[0];
  const float* ln_w    = (const float*)d_in[1];
  const float* ln_b    = (const float*)d_in[2];
  const float* temp    = (const float*)d_in[3];
  const float* q_w     = (const float*)d_in[4];
  const float* q_dw    = (const float*)d_in[5];
  const float* kv_w    = (const float*)d_in[6];
  const float* kv_dw   = (const float*)d_in[7];
  const float* proj_w  = (const float*)d_in[8];
  const float* pos_e   = (const float*)d_in[9];
  const float* posq_w  = (const float*)d_in[10];
  const float* posk_w  = (const float*)d_in[11];
  const float* selin_w = (const float*)d_in[12];
  const float* seldw_w = (const float*)d_in[13];
  const float* selout_w= (const float*)d_in[14];
  const float* alphaP  = (const float*)d_in[15];

  char* ws = (char*)d_ws;
  unsigned short* zerop  = (unsigned short*)(ws + 0);
  float* biasC           = (float*)(ws + 4096);
  float* Spos            = (float*)(ws + 8192);
  float* Scfa            = (float*)(ws + 794624);
  float* qnp             = (float*)(ws + 1581056);
  float* knp             = (float*)(ws + 1679360);
  float* att             = (float*)(ws + 1777664);
  unsigned short* WC     = (unsigned short*)(ws + 2097152);
  unsigned short* Wproj  = (unsigned short*)(ws + 2465792);
  unsigned short* Wselin = (unsigned short*)(ws + 2539520);
  unsigned short* Wselout= (unsigned short*)(ws + 4302080);
  float* WdwQKV          = (float*)(ws + 6071552);
  float* WdwSEL          = (float*)(ws + 6092288);
  // big regions (sequenced reuse):
  unsigned short* normx  = (unsigned short*)(ws + 8388608);   // 25.2MB -> outT
  unsigned short* outT   = normx;
  unsigned short* qpos   = (unsigned short*)(ws + 33554432);  // (n,384) 50.3MB -> x2 f32
  float*          x2     = (float*)(ws + 33554432);
  unsigned short* qkvsep = (unsigned short*)(ws + 83886080);  // (n,576) 75.5MB -> nx
  unsigned short* nx     = (unsigned short*)(ws + 83886080);  // 25.2MB
  unsigned short* g2     = (unsigned short*)(ws + 117440512); // (n,512) 67MB
  unsigned short* qkvd   = (unsigned short*)(ws + 184549376); // (n,576) 75.5MB -> g
  unsigned short* g      = qkvd;

  hipMemsetAsync(zerop, 0, 4096, stream);

  // weight prep
  prepw_k<<<864, 256, 0, stream>>>(posq_w, posk_w, q_w, kv_w, proj_w, WC, Wproj);
  prepselin_k<<<3443, 256, 0, stream>>>(selin_w, Wselin);
  prepselout_k<<<3456, 256, 0, stream>>>(selout_w, Wselout);
  prepbias_k<<<15, 64, 0, stream>>>(posq_w, posk_w, pos_e, biasC);
  prepdwT_k<<<39, 256, 0, stream>>>(q_dw, kv_dw, seldw_w, WdwQKV, WdwSEL);

  // LN1
  ln1_k<<<1024, 256, 0, stream>>>(x, ln_w, ln_b, normx);
  // combined pos_q/pos_k/q/kv GEMM (960 cols, bias on first 384), split outputs
  gemm_k<0><<<512*8, 256, 0, stream>>>(normx, 192, WC, 192, 960, 960, 384, 8,
                                       qpos, qkvsep, biasC, nullptr, nullptr, alphaP, zerop);
  // pos logits
  pairdot_k<<<192, 256, 0, stream>>>(qpos, qpos + 192, 384, Spos);
  // fused depthwise q,k,v -> qkvd (n,576)
  dw_k<72,0><<<18432, 256, 0, stream>>>(qkvsep, 576, WdwQKV, 576, qkvd, 576);
  // l2 norms (q and k partials in one launch)
  sumsq2_k<<<256, 192, 0, stream>>>(qkvd, qnp, knp);
  // cfa logits
  pairdot_k<<<192, 256, 0, stream>>>(qkvd, qkvd + 192, 576, Scfa);
  // softmaxes + combine
  smax_k<<<24, 64, 0, stream>>>(Spos, Scfa, qnp, knp, temp, att);
  // PV
  pv_k<<<24*256, 256, 0, stream>>>(att, qkvd + 384, 576, outT);
  // proj + residual -> x2 (f32, (n,c))
  gemm_k<1><<<512*2, 256, 0, stream>>>(outT, 192, Wproj, 192, 192, 192, 192, 2,
                                       nullptr, nullptr, nullptr, x, x2, alphaP, zerop);
  // LN2
  ln2_k<<<16384, 256, 0, stream>>>(x2, ln_w, ln_b, nx);
  // SEL in conv3x3 (K=1728): 256x256, 2Mx4N waves, 4-phase
  gemm256_k<0,9, 2,4, 8,4, 4><<<512, 512, 0, stream>>>(nx, 192, Wselin, 1728, 510, 512, 512, 2,
                                                       g, nullptr, nullptr, alphaP, zerop);
  // SEL depthwise + SiLU
  dw_k<64,1><<<16384, 256, 0, stream>>>(g, 512, WdwSEL, 512, g2, 512);
  // SEL out conv3x3 (K=4608): 256x192 tile (no padding waste), 4Mx2N waves, 4-phase
  gemm256_k<2,9, 4,2, 4,6, 3><<<256, 512, 0, stream>>>(g2, 512, Wselout, 4608, 192, 192, 0, 1,
                                                       nullptr, x2, (float*)d_out, alphaP, zerop);
}